// Round 7
// baseline (367.437 us; speedup 1.0000x reference)
//
#include <hip/hip_runtime.h>

#define NN 8192
#define DD 768
#define EE 131072
#define BBg 64
#define LLn 128
#define CCh 384

typedef unsigned short u16;
typedef unsigned char u8;
typedef __attribute__((ext_vector_type(8))) short short8;
typedef __attribute__((ext_vector_type(4))) float f32x4;

__device__ __forceinline__ float b2f(u16 u) {
    union { unsigned int i; float f; } x; x.i = ((unsigned int)u) << 16; return x.f;
}
__device__ __forceinline__ u16 f2b(float f) {
    union { float f; unsigned int i; } x; x.f = f;
    unsigned int r = x.i + 0x7fffu + ((x.i >> 16) & 1u);
    return (u16)(r >> 16);
}
__device__ __forceinline__ void gload16(const void* g, void* l) {
    __builtin_amdgcn_global_load_lds((const __attribute__((address_space(1))) void*)g,
                                     (__attribute__((address_space(3))) void*)l, 16, 0, 0);
}

// ---------------- prep: zero cnt + zero score + f32->bf16 convert (1 dispatch) ----------------
__global__ __launch_bounds__(256) void prep_kernel(const float* __restrict__ in,
                                                   u16* __restrict__ out,
                                                   unsigned int* __restrict__ cnt32,
                                                   float* __restrict__ score) {
    int i = blockIdx.x * 256 + threadIdx.x;   // grid 6144 blocks: i < NN*DD/4
    float4 v = ((const float4*)in)[i];
    ushort4 o; o.x = f2b(v.x); o.y = f2b(v.y); o.z = f2b(v.z); o.w = f2b(v.w);
    ((ushort4*)out)[i] = o;
    if (blockIdx.x < 1024) cnt32[i] = 0;                       // 1 MB cnt
    else if (blockIdx.x < 1056) score[i - 1024 * 256] = 0.f;   // 8192 floats
}

// ---------------- combo: weight transposes (z<11) + edge histogram (z=11) ----------------
struct TP { const float* src; u16* dst; int rowOff; };
struct TP11 { TP a[11]; };

__global__ __launch_bounds__(256) void combo_kernel(TP11 args,
                                                    const int* __restrict__ srcp,
                                                    const int* __restrict__ dstp,
                                                    unsigned int* __restrict__ cnt32) {
    __shared__ float tile[64][65];
    if (blockIdx.z == 11) {
        for (int e = blockIdx.x * 256 + threadIdx.x; e < EE; e += 144 * 256) {
            int d = dstp[e], s = srcp[e];
            int g = d >> 7;
            int idx = (g << 14) + ((d & 127) << 7) + (s & 127);
            atomicAdd(&cnt32[idx >> 2], 1u << ((idx & 3) * 8));
        }
        return;
    }
    TP tp = args.a[blockIdx.z];
    int bx = blockIdx.x % 12, by = blockIdx.x / 12;
    int n0 = bx * 64, k0 = by * 64;
    int t = threadIdx.x;
    int tc = t & 63, tr = t >> 6;
#pragma unroll
    for (int i = 0; i < 16; i++)
        tile[tr + i * 4][tc] = tp.src[(size_t)(tp.rowOff + k0 + tr + i * 4) * DD + n0 + tc];
    __syncthreads();
#pragma unroll
    for (int i = 0; i < 16; i++) {
        int row = tr + i * 4;
        tp.dst[(size_t)(n0 + row) * DD + k0 + tc] = f2b(tile[tc][row]);
    }
}

// ---------------- small GEMM (64x64 tile), for M=64 fc1 ----------------
enum { EPI_F32 = 1, EPI_TANH = 3 };

__global__ __launch_bounds__(256) void gemm_bf16(const u16* __restrict__ A,
                                                 const u16* __restrict__ Wt,
                                                 const float* __restrict__ bias,
                                                 void* __restrict__ outp, int K, int mode) {
    __shared__ u16 As[64][72];
    __shared__ u16 Bs[64][72];
    const int m0 = blockIdx.y * 64, n0 = blockIdx.x * 64;
    const int t = threadIdx.x;
    const int lane = t & 63, w = t >> 6;
    const int tr = t >> 2, tc = (t & 3) * 16;
    f32x4 acc[4] = {{0,0,0,0},{0,0,0,0},{0,0,0,0},{0,0,0,0}};
    const int fRow = lane & 15;
    const int fK = (lane >> 4) * 8;

    for (int k0 = 0; k0 < K; k0 += 64) {
        int4 a0 = *(const int4*)(A + (size_t)(m0 + tr) * K + k0 + tc);
        int4 a1 = *(const int4*)(A + (size_t)(m0 + tr) * K + k0 + tc + 8);
        int4 b0 = *(const int4*)(Wt + (size_t)(n0 + tr) * K + k0 + tc);
        int4 b1 = *(const int4*)(Wt + (size_t)(n0 + tr) * K + k0 + tc + 8);
        __syncthreads();
        *(int4*)&As[tr][tc] = a0; *(int4*)&As[tr][tc + 8] = a1;
        *(int4*)&Bs[tr][tc] = b0; *(int4*)&Bs[tr][tc + 8] = b1;
        __syncthreads();
#pragma unroll
        for (int s = 0; s < 2; s++) {
            short8 af = *(const short8*)&As[w * 16 + fRow][s * 32 + fK];
#pragma unroll
            for (int g = 0; g < 4; g++) {
                short8 bf = *(const short8*)&Bs[g * 16 + fRow][s * 32 + fK];
                acc[g] = __builtin_amdgcn_mfma_f32_16x16x32_bf16(af, bf, acc[g], 0, 0, 0);
            }
        }
    }
    const int colLocal = lane & 15;
    const int rowLocal = (lane >> 4) * 4;
#pragma unroll
    for (int g = 0; g < 4; g++) {
        int col = n0 + g * 16 + colLocal;
        float bv = bias ? bias[col] : 0.f;
#pragma unroll
        for (int i = 0; i < 4; i++) {
            int row = m0 + w * 16 + rowLocal + i;
            float v = acc[g][i] + bv;
            if (mode == EPI_TANH) v = tanhf(v);
            ((float*)outp)[(size_t)row * DD + col] = v;
        }
    }
}

// ---------------- QKVS GEMM: 256x128 tile, 8 waves, 3-slab + frag-prefetch (R2 best) ------
// Best-measured variant (50.8 us): K-tile split into 2 balanced sub-phases (8 ds_read +
// 16 MFMA each). Sub-phase p+1's reads are issued BEFORE sub-phase p's MFMA cluster;
// counted lgkmcnt(8) waits only current frags. Last sub-phase prefetches next tile's frags
// (mid-tile vmcnt(6)+barrier certifies staging). 2 barriers/tile. XCD-aware swizzle.
#define SLAB 24576   // u16 per slab: A 256x64 (16384) + B 128x64 (8192) = 48 KB
__global__ __launch_bounds__(512, 2) void gemm256(const u16* __restrict__ A,
                                                  const u16* __restrict__ Wt,
                                                  const float* __restrict__ b0,
                                                  const float* __restrict__ b1,
                                                  const float* __restrict__ b2,
                                                  const float* __restrict__ b3,
                                                  u16* __restrict__ o0, u16* __restrict__ o1,
                                                  u16* __restrict__ o2, u16* __restrict__ o3) {
    __shared__ u16 smem[3 * SLAB];   // 144 KB: 3 K-tile slabs; reused by epilogue staging
    const int K = DD;
    const int t = threadIdx.x;
    const int lane = t & 63, w = t >> 6;
    const int wr = w >> 1, wc = w & 1;          // 8 waves: 4M x 2N, 64x64 C per wave
    // XCD-aware bijective swizzle (768 = 8 XCD x 96; region = 8 by x 12 bx)
    const int id = blockIdx.y * 24 + blockIdx.x;
    const int xcd = id & 7, jj = id >> 3;
    const int by = (xcd >> 1) * 8 + jj / 12;
    const int bx = (xcd & 1) * 12 + jj % 12;
    const int m0 = by * 256, n0 = bx * 128;
    const int fRow = lane & 15, fThr = lane >> 4;
    const u16* Abase = A + (size_t)m0 * K;
    const u16* Bbase = Wt + (size_t)n0 * K;

    // stage full K-tile kt2 into slab (6 x global_load_lds; XOR-pre-swizzled source)
    auto stage = [&](u16* slab, int kt2) {
        const int k0 = kt2 * 64;
#pragma unroll
        for (int s = 0; s < 4; ++s) {
            int c = t + 512 * s;
            int row = c >> 3;
            int col = ((c & 7) ^ (row & 7)) * 8;
            gload16(Abase + (size_t)row * K + k0 + col, (char*)slab + (size_t)c * 16);
        }
#pragma unroll
        for (int s = 0; s < 2; ++s) {
            int c = t + 512 * s;
            int row = c >> 3;
            int col = ((c & 7) ^ (row & 7)) * 8;
            gload16(Bbase + (size_t)row * K + k0 + col, (char*)(slab + 16384) + (size_t)c * 16);
        }
    };
    // issue the 8 frag reads (4 A + 4 B) for K-half p of a slab
    auto loadFrags = [&](const u16* As, const u16* Bs, int p, short8* af, short8* bf) {
        const int cj = p * 4 + fThr;
#pragma unroll
        for (int i = 0; i < 4; ++i) {
            const int R = wr * 64 + i * 16 + fRow;
            af[i] = *(const short8*)&As[((size_t)R * 8 + (cj ^ (R & 7))) * 8];
        }
#pragma unroll
        for (int g = 0; g < 4; ++g) {
            const int Rb = wc * 64 + g * 16 + fRow;
            bf[g] = *(const short8*)&Bs[((size_t)Rb * 8 + (cj ^ (Rb & 7))) * 8];
        }
    };

    // prologue: tiles 0,1 in flight; wait tile 0 only; preload t0/sp0 frags
    stage(smem, 0);
    stage(smem + SLAB, 1);
    asm volatile("s_waitcnt vmcnt(6)" ::: "memory");
    __builtin_amdgcn_s_barrier();

    short8 afA[4], bfA[4], afB[4], bfB[4];
    loadFrags(smem, smem + 16384, 0, afA, bfA);

    f32x4 acc[4][4] = {};
    int cur = 0;
    for (int kt = 0; kt < 12; ++kt) {
        const u16* As = smem + cur * SLAB;
        const u16* Bs = As + 16384;
        int nx = cur + 2; if (nx >= 3) nx -= 3;
        int pv = cur + 1; if (pv >= 3) pv -= 3;
        if (kt < 10) stage(smem + nx * SLAB, kt + 2);   // into slab ≡ kt-1: safe after end-of-tile barrier

        // ---- sub-phase 0: issue sp1 reads, wait sp0 frags (counted), 16 MFMA ----
        loadFrags(As, Bs, 1, afB, bfB);
        asm volatile("s_waitcnt lgkmcnt(8)" ::: "memory");
        __builtin_amdgcn_sched_barrier(0);
        __builtin_amdgcn_s_setprio(1);
#pragma unroll
        for (int i = 0; i < 4; ++i)
#pragma unroll
            for (int g = 0; g < 4; ++g)
                acc[i][g] = __builtin_amdgcn_mfma_f32_16x16x32_bf16(afA[i], bfA[g], acc[i][g], 0, 0, 0);
        __builtin_amdgcn_s_setprio(0);

        // ---- mid-tile: certify next tile's slab fully staged (counted vmcnt) ----
        if (kt < 10) asm volatile("s_waitcnt vmcnt(6)" ::: "memory");
        else         asm volatile("s_waitcnt vmcnt(0)" ::: "memory");
        __builtin_amdgcn_s_barrier();

        // ---- sub-phase 1: prefetch next tile's sp0 frags, wait sp1 frags, 16 MFMA ----
        if (kt < 11) {
            loadFrags(smem + pv * SLAB, smem + pv * SLAB + 16384, 0, afA, bfA);
            asm volatile("s_waitcnt lgkmcnt(8)" ::: "memory");
        } else {
            asm volatile("s_waitcnt lgkmcnt(0)" ::: "memory");
        }
        __builtin_amdgcn_sched_barrier(0);
        __builtin_amdgcn_s_setprio(1);
#pragma unroll
        for (int i = 0; i < 4; ++i)
#pragma unroll
            for (int g = 0; g < 4; ++g)
                acc[i][g] = __builtin_amdgcn_mfma_f32_16x16x32_bf16(afB[i], bfB[g], acc[i][g], 0, 0, 0);
        __builtin_amdgcn_s_setprio(0);
        __builtin_amdgcn_s_barrier();   // end-of-tile: all slab-kt reads done -> next stage safe

        cur = pv;
    }

    // ---- epilogue: stage full 256x128 C tile through LDS -> coalesced ushort4 stores ----
    // 128-col tile never straddles a 768 boundary (768 = 6*128): one dest per block.
    const int chunk = n0 / DD;
    const float* bp = (chunk == 0) ? b0 : (chunk == 1) ? b1 : (chunk == 2) ? b2 : b3;
    u16* op = (chunk == 0) ? o0 : (chunk == 1) ? o1 : (chunk == 2) ? o2 : o3;
    const int cb0 = n0 - chunk * DD;
    if (chunk == 2) {
        // vT[col][node]: stage transposed 128 cols x 256 nodes
        u16 (*Vt)[264] = (u16(*)[264])smem;
#pragma unroll
        for (int g = 0; g < 4; g++) {
            float bv = bp[cb0 + wc * 64 + g * 16 + fRow];
#pragma unroll
            for (int i = 0; i < 4; i++)
#pragma unroll
                for (int rr = 0; rr < 4; rr++)
                    Vt[wc * 64 + g * 16 + fRow][wr * 64 + i * 16 + fThr * 4 + rr] =
                        f2b(acc[i][g][rr] + bv);
        }
        __syncthreads();
#pragma unroll
        for (int ii = 0; ii < 16; ii++) {
            int c = t + 512 * ii;                // 8192 chunks: col = c>>6, 8B node-chunk
            int col = c >> 6, ch = c & 63;
            *(ushort4*)(op + (size_t)(cb0 + col) * NN + m0 + ch * 4) =
                *(const ushort4*)&Vt[col][ch * 4];
        }
    } else {
        // row-major out[node][768]
        u16 (*Cs)[136] = (u16(*)[136])smem;
#pragma unroll
        for (int g = 0; g < 4; g++) {
            float bv = bp[cb0 + wc * 64 + g * 16 + fRow];
#pragma unroll
            for (int i = 0; i < 4; i++)
#pragma unroll
                for (int rr = 0; rr < 4; rr++)
                    Cs[wr * 64 + i * 16 + fThr * 4 + rr][wc * 64 + g * 16 + fRow] =
                        f2b(acc[i][g][rr] + bv);
        }
        __syncthreads();
#pragma unroll
        for (int ii = 0; ii < 16; ii++) {
            int c = t + 512 * ii;                // 8192 chunks: row = c>>5, 8B col-chunk
            int row = c >> 5, ch = c & 31;
            *(ushort4*)(op + (size_t)(m0 + row) * DD + cb0 + ch * 4) =
                *(const ushort4*)&Cs[row][ch * 4];
        }
    }
}

// ---------------- XC GEMM (128x128) + inline Aq + fused score reduction ----------------
__global__ __launch_bounds__(256) void gemm_xc(const u16* __restrict__ A,
                                               const u16* __restrict__ Wt,
                                               const u16* __restrict__ wt8,
                                               const float* __restrict__ atti_b,
                                               const float* __restrict__ atts_w,
                                               float* __restrict__ score) {
    __shared__ u16 As[128 * 64];
    __shared__ u16 Bs[128 * 64];
    __shared__ float aq_p[2][128];
    const int K = DD;
    const int t = threadIdx.x;
    const int lane = t & 63, w = t >> 6;
    const int wr = w >> 1, wc = w & 1;
    const int n0 = blockIdx.x * 128, m0 = blockIdx.y * 128;
    const int fRow = lane & 15, fThr = lane >> 4;

    {
        int col = t & 127, kh = t >> 7;
        const u16* xr = A + (size_t)m0 * DD + kh * 384;
        const u16* wr8 = wt8 + (size_t)(n0 + col) * DD + kh * 384;
        float s = 0.f;
#pragma unroll 8
        for (int j = 0; j < 96; j++) {
            ushort4 a4 = *(const ushort4*)(xr + j * 4);
            ushort4 b4 = *(const ushort4*)(wr8 + j * 4);
            s += b2f(a4.x) * b2f(b4.x) + b2f(a4.y) * b2f(b4.y)
               + b2f(a4.z) * b2f(b4.z) + b2f(a4.w) * b2f(b4.w);
        }
        aq_p[kh][col] = s;
    }

    f32x4 acc[4][4] = {};
    const u16* Abase = A + (size_t)m0 * K;
    const u16* Bbase = Wt + (size_t)n0 * K;
    for (int k0 = 0; k0 < K; k0 += 64) {
        __syncthreads();
#pragma unroll
        for (int i = 0; i < 4; i++) {
            int c = t + 256 * i;
            int row = c >> 3;
            int col = ((c & 7) ^ (row & 7)) * 8;
            gload16(Abase + (size_t)row * K + k0 + col, (char*)As + (size_t)c * 16);
            gload16(Bbase + (size_t)row * K + k0 + col, (char*)Bs + (size_t)c * 16);
        }
        __syncthreads();
#pragma unroll
        for (int kk = 0; kk < 64; kk += 32) {
            const int cjW = (kk >> 3) + fThr;
            short8 af[4], bf[4];
#pragma unroll
            for (int i = 0; i < 4; i++) {
                int R = wr * 64 + i * 16 + fRow;
                af[i] = *(const short8*)&As[(R * 8 + (cjW ^ (R & 7))) * 8];
            }
#pragma unroll
            for (int g = 0; g < 4; g++) {
                int R = wc * 64 + g * 16 + fRow;
                bf[g] = *(const short8*)&Bs[(R * 8 + (cjW ^ (R & 7))) * 8];
            }
#pragma unroll
            for (int i = 0; i < 4; i++)
#pragma unroll
                for (int g = 0; g < 4; g++)
                    acc[i][g] = __builtin_amdgcn_mfma_f32_16x16x32_bf16(af[i], bf[g], acc[i][g], 0, 0, 0);
        }
    }
    float rsum[4][4] = {};
#pragma unroll
    for (int g = 0; g < 4; g++) {
        int cl = wc * 64 + g * 16 + fRow;
        int col = n0 + cl;
        float bv = atti_b[col] + aq_p[0][cl] + aq_p[1][cl];
        float av = atts_w[col];
#pragma unroll
        for (int i = 0; i < 4; i++)
#pragma unroll
            for (int rr = 0; rr < 4; rr++) {
                float v = fmaxf(acc[i][g][rr] + bv, 0.f);
                rsum[i][rr] += v * av;
            }
    }
#pragma unroll
    for (int i = 0; i < 4; i++)
#pragma unroll
        for (int rr = 0; rr < 4; rr++) {
            float s = rsum[i][rr];
            s += __shfl_xor(s, 1, 16); s += __shfl_xor(s, 2, 16);
            s += __shfl_xor(s, 4, 16); s += __shfl_xor(s, 8, 16);
            if (fRow == 0)
                atomicAdd(&score[m0 + wr * 64 + i * 16 + fThr * 4 + rr], s);
        }
}

// ---------------- fused dense attention: barrier-free, direct-from-global fragments ------
// All operands L2-resident; MFMA fragments are 16B/lane contiguous in the existing global
// layouts (Q,K row-major; vT col-major). No LDS staging for Q/K/V, ZERO __syncthreads.
// QK^T: 12-step ping-pong (8 K-frag global loads in flight behind 8 MFMA, fully unrolled,
// static indexing per rule #20). P transpose stays wave-local in LDS (same-wave RAW,
// compiler-ordered). z = graph*2 + ccHalf (PV split; QK^T recomputed - it's latency-cheap).
__global__ __launch_bounds__(256, 2) void attn_fused(const u16* __restrict__ qb,
                                                     const u16* __restrict__ kb,
                                                     const u16* __restrict__ vT,
                                                     const u8* __restrict__ cnt,
                                                     const u16* __restrict__ hs,
                                                     u16* __restrict__ out) {
    __shared__ u16 Pl[64][136];
    const int half = blockIdx.x, hd = blockIdx.y;
    const int g = blockIdx.z >> 1, ch = blockIdx.z & 1;
    const int t = threadIdx.x;
    const int lane = t & 63, w = t >> 6;
    const int fRow = lane & 15, fThr = lane >> 4;
    const int dstBase = g * 128 + half * 64;
    const u16* Qb = qb + (size_t)dstBase * DD + hd * CCh;
    const u16* Kb = kb + (size_t)(g * 128) * DD + hd * CCh;

    // Q fragments for this wave's 16-row strip: step s -> k offset s*32 (k0=(s>>1)*64, kk=(s&1)*32)
    const u16* Qrow = Qb + (size_t)(w * 16 + fRow) * DD + fThr * 8;
    short8 qf[12];
#pragma unroll
    for (int s = 0; s < 12; ++s) qf[s] = *(const short8*)(Qrow + s * 32);

    const u16* Krow = Kb + fThr * 8;
    short8 bp[8], bq[8];
#pragma unroll
    for (int j = 0; j < 8; ++j)
        bp[j] = *(const short8*)(Krow + (size_t)(j * 16 + fRow) * DD);
#pragma unroll
    for (int j = 0; j < 8; ++j)
        bq[j] = *(const short8*)(Krow + (size_t)(j * 16 + fRow) * DD + 32);

    f32x4 acc[8] = {};
#pragma unroll
    for (int s = 0; s < 12; ++s) {
        if ((s & 1) == 0) {
#pragma unroll
            for (int j = 0; j < 8; ++j)
                acc[j] = __builtin_amdgcn_mfma_f32_16x16x32_bf16(qf[s], bp[j], acc[j], 0, 0, 0);
            if (s + 2 < 12) {
#pragma unroll
                for (int j = 0; j < 8; ++j)
                    bp[j] = *(const short8*)(Krow + (size_t)(j * 16 + fRow) * DD + (s + 2) * 32);
            }
        } else {
#pragma unroll
            for (int j = 0; j < 8; ++j)
                acc[j] = __builtin_amdgcn_mfma_f32_16x16x32_bf16(qf[s], bq[j], acc[j], 0, 0, 0);
            if (s + 2 < 12) {
#pragma unroll
                for (int j = 0; j < 8; ++j)
                    bq[j] = *(const short8*)(Krow + (size_t)(j * 16 + fRow) * DD + (s + 2) * 32);
            }
        }
    }

    const float scale = 0.05103103630798288f;  // 1/sqrt(384)
    const u8* cg = cnt + ((size_t)g << 14);
    const int rbase = half * 64 + w * 16 + fThr * 4;
    float pv[8][4];
#pragma unroll
    for (int i = 0; i < 4; i++) {
        float m = -3.4e38f;
#pragma unroll
        for (int j = 0; j < 8; j++) {
            float c = (float)cg[(rbase + i) * 128 + j * 16 + fRow];
            float s = acc[j][i] * scale;
            pv[j][i] = c;
            if (c > 0.f) m = fmaxf(m, s);
        }
#pragma unroll
        for (int msk = 1; msk <= 8; msk <<= 1) m = fmaxf(m, __shfl_xor(m, msk, 16));
        float sum = 0.f;
#pragma unroll
        for (int j = 0; j < 8; j++) {
            float p = (pv[j][i] > 0.f) ? pv[j][i] * __expf(acc[j][i] * scale - m) : 0.f;
            pv[j][i] = p; sum += p;
        }
#pragma unroll
        for (int msk = 1; msk <= 8; msk <<= 1) sum += __shfl_xor(sum, msk, 16);
        float inv = (sum > 0.f) ? 1.f / sum : 0.f;
#pragma unroll
        for (int j = 0; j < 8; j++)
            Pl[w * 16 + fThr * 4 + i][j * 16 + fRow] = f2b(pv[j][i] * inv);
    }

    // PV: V fragments direct from vT[col][node] (L2-resident); Pl read is same-wave.
    for (int cc = ch * 3; cc < ch * 3 + 3; cc++) {
        const u16* Vb = vT + (size_t)(hd * CCh + cc * 64) * NN + g * 128 + fThr * 8;
        f32x4 acc2[4] = {};
#pragma unroll
        for (int kk = 0; kk < 128; kk += 32) {
            short8 af = *(const short8*)&Pl[w * 16 + fRow][kk + fThr * 8];
#pragma unroll
            for (int j = 0; j < 4; j++) {
                short8 bf = *(const short8*)(Vb + (size_t)(j * 16 + fRow) * NN + kk);
                acc2[j] = __builtin_amdgcn_mfma_f32_16x16x32_bf16(af, bf, acc2[j], 0, 0, 0);
            }
        }
#pragma unroll
        for (int j = 0; j < 4; j++) {
            int c = hd * CCh + cc * 64 + j * 16 + fRow;
#pragma unroll
            for (int i = 0; i < 4; i++) {
                int row = dstBase + w * 16 + fThr * 4 + i;
                size_t idx = (size_t)row * DD + c;
                float r = fmaxf(acc2[j][i] + b2f(hs[idx]), 0.f);
                out[idx] = f2b(r);
            }
        }
    }
}

// ---------------- per-graph softmax + weighted pool -> bf16 (192 blocks) ----------------
__global__ __launch_bounds__(256) void pool_kernel(const float* __restrict__ score,
                                                   const u16* __restrict__ hx,
                                                   u16* __restrict__ pb) {
    int chunk = blockIdx.x, b = blockIdx.y, t = threadIdx.x;
    __shared__ float sprob[LLn];
    if (t < 64) {
        float s0 = score[b * LLn + t];
        float s1 = score[b * LLn + 64 + t];
        float mx = fmaxf(s0, s1);
#pragma unroll
        for (int m = 1; m <= 32; m <<= 1) mx = fmaxf(mx, __shfl_xor(mx, m, 64));
        float e0 = __expf(s0 - mx), e1 = __expf(s1 - mx);
        float sum = e0 + e1;
#pragma unroll
        for (int m = 1; m <= 32; m <<= 1) sum += __shfl_xor(sum, m, 64);
        float inv = 1.f / sum;
        sprob[t] = e0 * inv; sprob[t + 64] = e1 * inv;
    }
    __syncthreads();
    int c = chunk * 256 + t;
    float a = 0.f;
    for (int l = 0; l < LLn; l++)
        a += sprob[l] * b2f(hx[(size_t)(b * LLn + l) * DD + c]);
    pb[(size_t)b * DD + c] = f2b(a);
}

// ---------------- head tail: fc2 + log_softmax ----------------
__global__ __launch_bounds__(256) void head2_kernel(const float* __restrict__ u,
                                                    const float* __restrict__ fc2w,
                                                    const float* __restrict__ fc2b,
                                                    float* __restrict__ outp) {
    int b = blockIdx.x, t = threadIdx.x;
    __shared__ float sred[4][3];
    float p0 = 0, p1 = 0, p2 = 0;
    for (int k = t; k < DD; k += 256) {
        float uv = u[(size_t)b * DD + k];
        p0 += uv * fc2w[k * 3 + 0]; p1 += uv * fc2w[k * 3 + 1]; p2 += uv * fc2w[k * 3 + 2];
    }
#pragma unroll
    for (int m = 1; m <= 32; m <<= 1) {
        p0 += __shfl_xor(p0, m, 64); p1 += __shfl_xor(p1, m, 64); p2 += __shfl_xor(p2, m, 64);
    }
    int w = t >> 6, lane = t & 63;
    if (lane == 0) { sred[w][0] = p0; sred[w][1] = p1; sred[w][2] = p2; }
    __syncthreads();
    if (t == 0) {
        float z0 = fc2b[0], z1 = fc2b[1], z2 = fc2b[2];
        for (int i = 0; i < 4; i++) { z0 += sred[i][0]; z1 += sred[i][1]; z2 += sred[i][2]; }
        float mx = fmaxf(z0, fmaxf(z1, z2));
        float lse = mx + logf(__expf(z0 - mx) + __expf(z1 - mx) + __expf(z2 - mx));
        outp[b * 3 + 0] = z0 - lse; outp[b * 3 + 1] = z1 - lse; outp[b * 3 + 2] = z2 - lse;
    }
}

// ---------------- launch ----------------
static inline char* carve(char*& p, size_t bytes) {
    char* r = p;
    p += (bytes + 255) & ~(size_t)255;
    return r;
}

extern "C" void kernel_launch(void* const* d_in, const int* in_sizes, int n_in,
                              void* d_out, int out_size, void* d_ws, size_t ws_size,
                              hipStream_t stream) {
    const float* x = (const float*)d_in[0];
    const int* ei = (const int*)d_in[1];
    const int* srcp = ei;
    const int* dstp = ei + EE;
    const float* wL[8] = {(const float*)d_in[2], (const float*)d_in[4], (const float*)d_in[6],
                          (const float*)d_in[8], (const float*)d_in[10], (const float*)d_in[12],
                          (const float*)d_in[14], (const float*)d_in[16]};
    const float* bL[8] = {(const float*)d_in[3], (const float*)d_in[5], (const float*)d_in[7],
                          (const float*)d_in[9], (const float*)d_in[11], (const float*)d_in[13],
                          (const float*)d_in[15], (const float*)d_in[17]};
    const float* atti_w = (const float*)d_in[18];
    const float* atti_b = (const float*)d_in[19];
    const float* atts_w = (const float*)d_in[20];
    const float* fc1_w = (const float*)d_in[22];
    const float* fc1_b = (const float*)d_in[23];
    const float* fc2_w = (const float*)d_in[24];
    const float* fc2_b = (const float*)d_in[25];
    float* outp = (float*)d_out;

    char* p = (char*)d_ws;
    const size_t ndb = (size_t)NN * DD * 2;
    const size_t wsz = (size_t)DD * DD * 2;
    u16* qb = (u16*)carve(p, ndb);
    u16* kb = (u16*)carve(p, ndb);
    u16* vt = (u16*)carve(p, ndb);   // V transposed [768][8192]
    u16* xb = (u16*)carve(p, ndb);   // layer1 input; reused as layer2 attn output (hp)
    u16* hb = (u16*)carve(p, ndb);   // layer1 attn output
    u16* hs = (u16*)carve(p, ndb);   // skip bf16
    u16* wtcat1 = (u16*)carve(p, wsz * 4);
    u16* wtcat2 = (u16*)carve(p, wsz * 4);
    u16* wt8 = (u16*)carve(p, wsz);
    u16* wt9 = (u16*)carve(p, wsz);
    u16* wtfc1 = (u16*)carve(p, wsz);
    u16* pb = (u16*)carve(p, (size_t)BBg * DD * 2);
    float* uu = (float*)carve(p, (size_t)BBg * DD * 4);
    u8* cnt = (u8*)carve(p, (size_t)BBg * 128 * 128);
    float* score = (float*)carve(p, NN * 4);

    // 1) prep: zero cnt/score + convert x -> bf16
    prep_kernel<<<6144, 256, 0, stream>>>(x, xb, (unsigned int*)cnt, score);

    // 2) combo: 11 transposes + cnt histogram
    TP11 tps;
    for (int i = 0; i < 4; i++) tps.a[i] = {wL[i], wtcat1 + (size_t)i * DD * DD, 0};
    for (int i = 0; i < 4; i++) tps.a[4 + i] = {wL[4 + i], wtcat2 + (size_t)i * DD * DD, 0};
    tps.a[8] = {atti_w, wt8, 0};
    tps.a[9] = {atti_w, wt9, DD};
    tps.a[10] = {fc1_w, wtfc1, 0};
    combo_kernel<<<dim3(144, 1, 12), 256, 0, stream>>>(tps, srcp, dstp, (unsigned int*)cnt);

    dim3 gf(24, 32);           // QKVS: N=3072/128, M=8192/256
    dim3 ga(2, 2, BBg * 2);    // attention: (dst-half, head, graph x ccHalf)
    // 3-4) layer 1
    gemm256<<<gf, 512, 0, stream>>>(xb, wtcat1, bL[0], bL[1], bL[2], bL[3], qb, kb, vt, hs);
    attn_fused<<<ga, 256, 0, stream>>>(qb, kb, vt, cnt, hs, hb);
    // 5-6) layer 2
    gemm256<<<gf, 512, 0, stream>>>(hb, wtcat2, bL[4], bL[5], bL[6], bL[7], qb, kb, vt, hs);
    attn_fused<<<ga, 256, 0, stream>>>(qb, kb, vt, cnt, hs, xb);   // xb = hp bf16

    // 7) pooling scores: XC with inline Aq + fused score reduction
    gemm_xc<<<dim3(6, 64), 256, 0, stream>>>(xb, wt9, wt8, atti_b, atts_w, score);

    // 8-10) tail: pool -> bf16, fc1 MFMA gemm (tanh), fc2+log_softmax
    pool_kernel<<<dim3(3, BBg), 256, 0, stream>>>(score, xb, pb);
    gemm_bf16<<<dim3(12, 1), 256, 0, stream>>>(pb, wtfc1, fc1_b, uu, DD, EPI_TANH);
    head2_kernel<<<BBg, 256, 0, stream>>>(uu, fc2_w, fc2_b, outp);
}

// Round 8
// 327.359 us; speedup vs baseline: 1.1224x; 1.1224x over previous
//
#include <hip/hip_runtime.h>

#define NN 8192
#define DD 768
#define EE 131072
#define BBg 64
#define LLn 128
#define CCh 384

typedef unsigned short u16;
typedef unsigned char u8;
typedef __attribute__((ext_vector_type(8))) short short8;
typedef __attribute__((ext_vector_type(4))) float f32x4;

__device__ __forceinline__ float b2f(u16 u) {
    union { unsigned int i; float f; } x; x.i = ((unsigned int)u) << 16; return x.f;
}
__device__ __forceinline__ u16 f2b(float f) {
    union { float f; unsigned int i; } x; x.f = f;
    unsigned int r = x.i + 0x7fffu + ((x.i >> 16) & 1u);
    return (u16)(r >> 16);
}
__device__ __forceinline__ void gload16(const void* g, void* l) {
    __builtin_amdgcn_global_load_lds((const __attribute__((address_space(1))) void*)g,
                                     (__attribute__((address_space(3))) void*)l, 16, 0, 0);
}

// ---------------- prep: zero cnt + zero score + f32->bf16 convert (1 dispatch) ----------------
__global__ __launch_bounds__(256) void prep_kernel(const float* __restrict__ in,
                                                   u16* __restrict__ out,
                                                   unsigned int* __restrict__ cnt32,
                                                   float* __restrict__ score) {
    int i = blockIdx.x * 256 + threadIdx.x;   // grid 6144 blocks: i < NN*DD/4
    float4 v = ((const float4*)in)[i];
    ushort4 o; o.x = f2b(v.x); o.y = f2b(v.y); o.z = f2b(v.z); o.w = f2b(v.w);
    ((ushort4*)out)[i] = o;
    if (blockIdx.x < 1024) cnt32[i] = 0;                       // 1 MB cnt
    else if (blockIdx.x < 1056) score[i - 1024 * 256] = 0.f;   // 8192 floats
}

// ---------------- combo: weight transposes (z<11) + edge histogram (z=11) ----------------
struct TP { const float* src; u16* dst; int rowOff; };
struct TP11 { TP a[11]; };

__global__ __launch_bounds__(256) void combo_kernel(TP11 args,
                                                    const int* __restrict__ srcp,
                                                    const int* __restrict__ dstp,
                                                    unsigned int* __restrict__ cnt32) {
    __shared__ float tile[64][65];
    if (blockIdx.z == 11) {
        for (int e = blockIdx.x * 256 + threadIdx.x; e < EE; e += 144 * 256) {
            int d = dstp[e], s = srcp[e];
            int g = d >> 7;
            int idx = (g << 14) + ((d & 127) << 7) + (s & 127);
            atomicAdd(&cnt32[idx >> 2], 1u << ((idx & 3) * 8));
        }
        return;
    }
    TP tp = args.a[blockIdx.z];
    int bx = blockIdx.x % 12, by = blockIdx.x / 12;
    int n0 = bx * 64, k0 = by * 64;
    int t = threadIdx.x;
    int tc = t & 63, tr = t >> 6;
#pragma unroll
    for (int i = 0; i < 16; i++)
        tile[tr + i * 4][tc] = tp.src[(size_t)(tp.rowOff + k0 + tr + i * 4) * DD + n0 + tc];
    __syncthreads();
#pragma unroll
    for (int i = 0; i < 16; i++) {
        int row = tr + i * 4;
        tp.dst[(size_t)(n0 + row) * DD + k0 + tc] = f2b(tile[tc][row]);
    }
}

// ---------------- fc1 GEMM, K-split for occupancy: grid (12 n-blocks, 6 K-chunks) ---------
// Old gemm_bf16 ran 12 blocks = 12 CUs (latency-exposed). Each block now computes a
// 64x64 tile over a 128-wide K-chunk and stores a partial f32 slab uu[kz][64][768];
// head2 sums slabs + fc1 bias + tanh (exact: tanh moved past linear accumulation).
__global__ __launch_bounds__(256) void fc1_kernel(const u16* __restrict__ A,
                                                  const u16* __restrict__ Wt,
                                                  float* __restrict__ uu) {
    __shared__ u16 As[64][72];
    __shared__ u16 Bs[64][72];
    const int n0 = blockIdx.x * 64;
    const int kz = blockIdx.y;
    const int t = threadIdx.x;
    const int lane = t & 63, w = t >> 6;
    const int tr = t >> 2, tc = (t & 3) * 16;
    f32x4 acc[4] = {{0,0,0,0},{0,0,0,0},{0,0,0,0},{0,0,0,0}};
    const int fRow = lane & 15;
    const int fK = (lane >> 4) * 8;

    for (int k0 = kz * 128; k0 < kz * 128 + 128; k0 += 64) {
        int4 a0 = *(const int4*)(A + (size_t)tr * DD + k0 + tc);
        int4 a1 = *(const int4*)(A + (size_t)tr * DD + k0 + tc + 8);
        int4 b0 = *(const int4*)(Wt + (size_t)(n0 + tr) * DD + k0 + tc);
        int4 b1 = *(const int4*)(Wt + (size_t)(n0 + tr) * DD + k0 + tc + 8);
        __syncthreads();
        *(int4*)&As[tr][tc] = a0; *(int4*)&As[tr][tc + 8] = a1;
        *(int4*)&Bs[tr][tc] = b0; *(int4*)&Bs[tr][tc + 8] = b1;
        __syncthreads();
#pragma unroll
        for (int s = 0; s < 2; s++) {
            short8 af = *(const short8*)&As[w * 16 + fRow][s * 32 + fK];
#pragma unroll
            for (int g = 0; g < 4; g++) {
                short8 bf = *(const short8*)&Bs[g * 16 + fRow][s * 32 + fK];
                acc[g] = __builtin_amdgcn_mfma_f32_16x16x32_bf16(af, bf, acc[g], 0, 0, 0);
            }
        }
    }
    const int colLocal = lane & 15;
    const int rowLocal = (lane >> 4) * 4;
#pragma unroll
    for (int g = 0; g < 4; g++) {
        int col = n0 + g * 16 + colLocal;
#pragma unroll
        for (int i = 0; i < 4; i++) {
            int row = w * 16 + rowLocal + i;
            uu[(size_t)kz * 64 * DD + (size_t)row * DD + col] = acc[g][i];
        }
    }
}

// ---------------- QKVS GEMM: 256x128 tile, 8 waves, 3-slab + frag-prefetch (R2 best) ------
#define SLAB 24576   // u16 per slab: A 256x64 (16384) + B 128x64 (8192) = 48 KB
__global__ __launch_bounds__(512, 2) void gemm256(const u16* __restrict__ A,
                                                  const u16* __restrict__ Wt,
                                                  const float* __restrict__ b0,
                                                  const float* __restrict__ b1,
                                                  const float* __restrict__ b2,
                                                  const float* __restrict__ b3,
                                                  u16* __restrict__ o0, u16* __restrict__ o1,
                                                  u16* __restrict__ o2, u16* __restrict__ o3) {
    __shared__ u16 smem[3 * SLAB];   // 144 KB: 3 K-tile slabs; reused by epilogue staging
    const int K = DD;
    const int t = threadIdx.x;
    const int lane = t & 63, w = t >> 6;
    const int wr = w >> 1, wc = w & 1;          // 8 waves: 4M x 2N, 64x64 C per wave
    // XCD-aware bijective swizzle (768 = 8 XCD x 96; region = 8 by x 12 bx)
    const int id = blockIdx.y * 24 + blockIdx.x;
    const int xcd = id & 7, jj = id >> 3;
    const int by = (xcd >> 1) * 8 + jj / 12;
    const int bx = (xcd & 1) * 12 + jj % 12;
    const int m0 = by * 256, n0 = bx * 128;
    const int fRow = lane & 15, fThr = lane >> 4;
    const u16* Abase = A + (size_t)m0 * K;
    const u16* Bbase = Wt + (size_t)n0 * K;

    auto stage = [&](u16* slab, int kt2) {
        const int k0 = kt2 * 64;
#pragma unroll
        for (int s = 0; s < 4; ++s) {
            int c = t + 512 * s;
            int row = c >> 3;
            int col = ((c & 7) ^ (row & 7)) * 8;
            gload16(Abase + (size_t)row * K + k0 + col, (char*)slab + (size_t)c * 16);
        }
#pragma unroll
        for (int s = 0; s < 2; ++s) {
            int c = t + 512 * s;
            int row = c >> 3;
            int col = ((c & 7) ^ (row & 7)) * 8;
            gload16(Bbase + (size_t)row * K + k0 + col, (char*)(slab + 16384) + (size_t)c * 16);
        }
    };
    auto loadFrags = [&](const u16* As, const u16* Bs, int p, short8* af, short8* bf) {
        const int cj = p * 4 + fThr;
#pragma unroll
        for (int i = 0; i < 4; ++i) {
            const int R = wr * 64 + i * 16 + fRow;
            af[i] = *(const short8*)&As[((size_t)R * 8 + (cj ^ (R & 7))) * 8];
        }
#pragma unroll
        for (int g = 0; g < 4; ++g) {
            const int Rb = wc * 64 + g * 16 + fRow;
            bf[g] = *(const short8*)&Bs[((size_t)Rb * 8 + (cj ^ (Rb & 7))) * 8];
        }
    };

    stage(smem, 0);
    stage(smem + SLAB, 1);
    asm volatile("s_waitcnt vmcnt(6)" ::: "memory");
    __builtin_amdgcn_s_barrier();

    short8 afA[4], bfA[4], afB[4], bfB[4];
    loadFrags(smem, smem + 16384, 0, afA, bfA);

    f32x4 acc[4][4] = {};
    int cur = 0;
    for (int kt = 0; kt < 12; ++kt) {
        const u16* As = smem + cur * SLAB;
        const u16* Bs = As + 16384;
        int nx = cur + 2; if (nx >= 3) nx -= 3;
        int pv = cur + 1; if (pv >= 3) pv -= 3;
        if (kt < 10) stage(smem + nx * SLAB, kt + 2);   // into slab ≡ kt-1: safe after end-of-tile barrier

        loadFrags(As, Bs, 1, afB, bfB);
        asm volatile("s_waitcnt lgkmcnt(8)" ::: "memory");
        __builtin_amdgcn_sched_barrier(0);
        __builtin_amdgcn_s_setprio(1);
#pragma unroll
        for (int i = 0; i < 4; ++i)
#pragma unroll
            for (int g = 0; g < 4; ++g)
                acc[i][g] = __builtin_amdgcn_mfma_f32_16x16x32_bf16(afA[i], bfA[g], acc[i][g], 0, 0, 0);
        __builtin_amdgcn_s_setprio(0);

        if (kt < 10) asm volatile("s_waitcnt vmcnt(6)" ::: "memory");
        else         asm volatile("s_waitcnt vmcnt(0)" ::: "memory");
        __builtin_amdgcn_s_barrier();

        if (kt < 11) {
            loadFrags(smem + pv * SLAB, smem + pv * SLAB + 16384, 0, afA, bfA);
            asm volatile("s_waitcnt lgkmcnt(8)" ::: "memory");
        } else {
            asm volatile("s_waitcnt lgkmcnt(0)" ::: "memory");
        }
        __builtin_amdgcn_sched_barrier(0);
        __builtin_amdgcn_s_setprio(1);
#pragma unroll
        for (int i = 0; i < 4; ++i)
#pragma unroll
            for (int g = 0; g < 4; ++g)
                acc[i][g] = __builtin_amdgcn_mfma_f32_16x16x32_bf16(afB[i], bfB[g], acc[i][g], 0, 0, 0);
        __builtin_amdgcn_s_setprio(0);
        __builtin_amdgcn_s_barrier();

        cur = pv;
    }

    // ---- epilogue: stage full 256x128 C tile through LDS -> coalesced ushort4 stores ----
    const int chunk = n0 / DD;
    const float* bp = (chunk == 0) ? b0 : (chunk == 1) ? b1 : (chunk == 2) ? b2 : b3;
    u16* op = (chunk == 0) ? o0 : (chunk == 1) ? o1 : (chunk == 2) ? o2 : o3;
    const int cb0 = n0 - chunk * DD;
    if (chunk == 2) {
        u16 (*Vt)[264] = (u16(*)[264])smem;
#pragma unroll
        for (int g = 0; g < 4; g++) {
            float bv = bp[cb0 + wc * 64 + g * 16 + fRow];
#pragma unroll
            for (int i = 0; i < 4; i++)
#pragma unroll
                for (int rr = 0; rr < 4; rr++)
                    Vt[wc * 64 + g * 16 + fRow][wr * 64 + i * 16 + fThr * 4 + rr] =
                        f2b(acc[i][g][rr] + bv);
        }
        __syncthreads();
#pragma unroll
        for (int ii = 0; ii < 16; ii++) {
            int c = t + 512 * ii;
            int col = c >> 6, ch = c & 63;
            *(ushort4*)(op + (size_t)(cb0 + col) * NN + m0 + ch * 4) =
                *(const ushort4*)&Vt[col][ch * 4];
        }
    } else {
        u16 (*Cs)[136] = (u16(*)[136])smem;
#pragma unroll
        for (int g = 0; g < 4; g++) {
            float bv = bp[cb0 + wc * 64 + g * 16 + fRow];
#pragma unroll
            for (int i = 0; i < 4; i++)
#pragma unroll
                for (int rr = 0; rr < 4; rr++)
                    Cs[wr * 64 + i * 16 + fThr * 4 + rr][wc * 64 + g * 16 + fRow] =
                        f2b(acc[i][g][rr] + bv);
        }
        __syncthreads();
#pragma unroll
        for (int ii = 0; ii < 16; ii++) {
            int c = t + 512 * ii;
            int row = c >> 5, ch = c & 31;
            *(ushort4*)(op + (size_t)(m0 + row) * DD + cb0 + ch * 4) =
                *(const ushort4*)&Cs[row][ch * 4];
        }
    }
}

// ---------------- XC GEMM (128x128) + inline Aq + fused score reduction ----------------
__global__ __launch_bounds__(256) void gemm_xc(const u16* __restrict__ A,
                                               const u16* __restrict__ Wt,
                                               const u16* __restrict__ wt8,
                                               const float* __restrict__ atti_b,
                                               const float* __restrict__ atts_w,
                                               float* __restrict__ score) {
    __shared__ u16 As[128 * 64];
    __shared__ u16 Bs[128 * 64];
    __shared__ float aq_p[2][128];
    const int K = DD;
    const int t = threadIdx.x;
    const int lane = t & 63, w = t >> 6;
    const int wr = w >> 1, wc = w & 1;
    const int n0 = blockIdx.x * 128, m0 = blockIdx.y * 128;
    const int fRow = lane & 15, fThr = lane >> 4;

    {
        int col = t & 127, kh = t >> 7;
        const u16* xr = A + (size_t)m0 * DD + kh * 384;
        const u16* wr8 = wt8 + (size_t)(n0 + col) * DD + kh * 384;
        float s = 0.f;
#pragma unroll 8
        for (int j = 0; j < 96; j++) {
            ushort4 a4 = *(const ushort4*)(xr + j * 4);
            ushort4 b4 = *(const ushort4*)(wr8 + j * 4);
            s += b2f(a4.x) * b2f(b4.x) + b2f(a4.y) * b2f(b4.y)
               + b2f(a4.z) * b2f(b4.z) + b2f(a4.w) * b2f(b4.w);
        }
        aq_p[kh][col] = s;
    }

    f32x4 acc[4][4] = {};
    const u16* Abase = A + (size_t)m0 * K;
    const u16* Bbase = Wt + (size_t)n0 * K;
    for (int k0 = 0; k0 < K; k0 += 64) {
        __syncthreads();
#pragma unroll
        for (int i = 0; i < 4; i++) {
            int c = t + 256 * i;
            int row = c >> 3;
            int col = ((c & 7) ^ (row & 7)) * 8;
            gload16(Abase + (size_t)row * K + k0 + col, (char*)As + (size_t)c * 16);
            gload16(Bbase + (size_t)row * K + k0 + col, (char*)Bs + (size_t)c * 16);
        }
        __syncthreads();
#pragma unroll
        for (int kk = 0; kk < 64; kk += 32) {
            const int cjW = (kk >> 3) + fThr;
            short8 af[4], bf[4];
#pragma unroll
            for (int i = 0; i < 4; i++) {
                int R = wr * 64 + i * 16 + fRow;
                af[i] = *(const short8*)&As[(R * 8 + (cjW ^ (R & 7))) * 8];
            }
#pragma unroll
            for (int g = 0; g < 4; g++) {
                int R = wc * 64 + g * 16 + fRow;
                bf[g] = *(const short8*)&Bs[(R * 8 + (cjW ^ (R & 7))) * 8];
            }
#pragma unroll
            for (int i = 0; i < 4; i++)
#pragma unroll
                for (int g = 0; g < 4; g++)
                    acc[i][g] = __builtin_amdgcn_mfma_f32_16x16x32_bf16(af[i], bf[g], acc[i][g], 0, 0, 0);
        }
    }
    float rsum[4][4] = {};
#pragma unroll
    for (int g = 0; g < 4; g++) {
        int cl = wc * 64 + g * 16 + fRow;
        int col = n0 + cl;
        float bv = atti_b[col] + aq_p[0][cl] + aq_p[1][cl];
        float av = atts_w[col];
#pragma unroll
        for (int i = 0; i < 4; i++)
#pragma unroll
            for (int rr = 0; rr < 4; rr++) {
                float v = fmaxf(acc[i][g][rr] + bv, 0.f);
                rsum[i][rr] += v * av;
            }
    }
#pragma unroll
    for (int i = 0; i < 4; i++)
#pragma unroll
        for (int rr = 0; rr < 4; rr++) {
            float s = rsum[i][rr];
            s += __shfl_xor(s, 1, 16); s += __shfl_xor(s, 2, 16);
            s += __shfl_xor(s, 4, 16); s += __shfl_xor(s, 8, 16);
            if (fRow == 0)
                atomicAdd(&score[m0 + wr * 64 + i * 16 + fThr * 4 + rr], s);
        }
}

// ---------------- fused dense attention: LDS-staged, cc-split for 2 blocks/CU (R6 best) ---
// z = graph*2 + ccHalf. Each block recomputes QK^T+softmax (cheap) and does PV for 3 of
// the 6 cc chunks -> 512 blocks = 2 blocks/CU, 2 waves/SIMD.
__global__ __launch_bounds__(256, 2) void attn_fused(const u16* __restrict__ qb,
                                                  const u16* __restrict__ kb,
                                                  const u16* __restrict__ vT,
                                                  const u8* __restrict__ cnt,
                                                  const u16* __restrict__ hs,
                                                  u16* __restrict__ out) {
    __shared__ u16 As[64][72];
    __shared__ u16 Bs[128][72];
    __shared__ u16 Pl[64][136];
    __shared__ u16 Vt[64][136];
    const int half = blockIdx.x, hd = blockIdx.y;
    const int g = blockIdx.z >> 1, ch = blockIdx.z & 1;
    const int t = threadIdx.x;
    const int lane = t & 63, w = t >> 6;
    const int fRow = lane & 15, fThr = lane >> 4;
    const int dstBase = g * 128 + half * 64;
    const u16* Qb = qb + (size_t)dstBase * DD + hd * CCh;
    const u16* Kb = kb + (size_t)(g * 128) * DD + hd * CCh;

    f32x4 acc[8] = {};
    const int trA = t >> 2, tcA = (t & 3) * 16;
    const int trB = t >> 1, tcB = (t & 1) * 32;
    for (int k0 = 0; k0 < CCh; k0 += 64) {
        int4 a0 = *(const int4*)(Qb + (size_t)trA * DD + k0 + tcA);
        int4 a1 = *(const int4*)(Qb + (size_t)trA * DD + k0 + tcA + 8);
        int4 b0 = *(const int4*)(Kb + (size_t)trB * DD + k0 + tcB);
        int4 b1 = *(const int4*)(Kb + (size_t)trB * DD + k0 + tcB + 8);
        int4 b2 = *(const int4*)(Kb + (size_t)trB * DD + k0 + tcB + 16);
        int4 b3 = *(const int4*)(Kb + (size_t)trB * DD + k0 + tcB + 24);
        __syncthreads();
        *(int4*)&As[trA][tcA] = a0; *(int4*)&As[trA][tcA + 8] = a1;
        *(int4*)&Bs[trB][tcB] = b0; *(int4*)&Bs[trB][tcB + 8] = b1;
        *(int4*)&Bs[trB][tcB + 16] = b2; *(int4*)&Bs[trB][tcB + 24] = b3;
        __syncthreads();
#pragma unroll
        for (int kk = 0; kk < 64; kk += 32) {
            short8 af = *(const short8*)&As[w * 16 + fRow][kk + fThr * 8];
#pragma unroll
            for (int j = 0; j < 8; j++) {
                short8 bf = *(const short8*)&Bs[j * 16 + fRow][kk + fThr * 8];
                acc[j] = __builtin_amdgcn_mfma_f32_16x16x32_bf16(af, bf, acc[j], 0, 0, 0);
            }
        }
    }

    const float scale = 0.05103103630798288f;  // 1/sqrt(384)
    const u8* cg = cnt + ((size_t)g << 14);
    const int rbase = half * 64 + w * 16 + fThr * 4;
    float pv[8][4];
#pragma unroll
    for (int i = 0; i < 4; i++) {
        float m = -3.4e38f;
#pragma unroll
        for (int j = 0; j < 8; j++) {
            float c = (float)cg[(rbase + i) * 128 + j * 16 + fRow];
            float s = acc[j][i] * scale;
            pv[j][i] = c;
            if (c > 0.f) m = fmaxf(m, s);
        }
#pragma unroll
        for (int msk = 1; msk <= 8; msk <<= 1) m = fmaxf(m, __shfl_xor(m, msk, 16));
        float sum = 0.f;
#pragma unroll
        for (int j = 0; j < 8; j++) {
            float p = (pv[j][i] > 0.f) ? pv[j][i] * __expf(acc[j][i] * scale - m) : 0.f;
            pv[j][i] = p; sum += p;
        }
#pragma unroll
        for (int msk = 1; msk <= 8; msk <<= 1) sum += __shfl_xor(sum, msk, 16);
        float inv = (sum > 0.f) ? 1.f / sum : 0.f;
#pragma unroll
        for (int j = 0; j < 8; j++)
            Pl[w * 16 + fThr * 4 + i][j * 16 + fRow] = f2b(pv[j][i] * inv);
    }

    for (int cc = ch * 3; cc < ch * 3 + 3; cc++) {
        __syncthreads();
#pragma unroll
        for (int ii = 0; ii < 4; ii++) {
            int q = t + 256 * ii;
            int row = q >> 4, col = (q & 15) * 8;
            *(int4*)&Vt[row][col] =
                *(const int4*)(vT + (size_t)(hd * CCh + cc * 64 + row) * NN + g * 128 + col);
        }
        __syncthreads();
        f32x4 acc2[4] = {};
#pragma unroll
        for (int kk = 0; kk < 128; kk += 32) {
            short8 af = *(const short8*)&Pl[w * 16 + fRow][kk + fThr * 8];
#pragma unroll
            for (int j = 0; j < 4; j++) {
                short8 bf = *(const short8*)&Vt[j * 16 + fRow][kk + fThr * 8];
                acc2[j] = __builtin_amdgcn_mfma_f32_16x16x32_bf16(af, bf, acc2[j], 0, 0, 0);
            }
        }
#pragma unroll
        for (int j = 0; j < 4; j++) {
            int c = hd * CCh + cc * 64 + j * 16 + fRow;
#pragma unroll
            for (int i = 0; i < 4; i++) {
                int row = dstBase + w * 16 + fThr * 4 + i;
                size_t idx = (size_t)row * DD + c;
                float r = fmaxf(acc2[j][i] + b2f(hs[idx]), 0.f);
                out[idx] = f2b(r);
            }
        }
    }
}

// ---------------- per-graph softmax + weighted pool -> bf16 (192 blocks) ----------------
__global__ __launch_bounds__(256) void pool_kernel(const float* __restrict__ score,
                                                   const u16* __restrict__ hx,
                                                   u16* __restrict__ pb) {
    int chunk = blockIdx.x, b = blockIdx.y, t = threadIdx.x;
    __shared__ float sprob[LLn];
    if (t < 64) {
        float s0 = score[b * LLn + t];
        float s1 = score[b * LLn + 64 + t];
        float mx = fmaxf(s0, s1);
#pragma unroll
        for (int m = 1; m <= 32; m <<= 1) mx = fmaxf(mx, __shfl_xor(mx, m, 64));
        float e0 = __expf(s0 - mx), e1 = __expf(s1 - mx);
        float sum = e0 + e1;
#pragma unroll
        for (int m = 1; m <= 32; m <<= 1) sum += __shfl_xor(sum, m, 64);
        float inv = 1.f / sum;
        sprob[t] = e0 * inv; sprob[t + 64] = e1 * inv;
    }
    __syncthreads();
    int c = chunk * 256 + t;
    float a = 0.f;
    for (int l = 0; l < LLn; l++)
        a += sprob[l] * b2f(hx[(size_t)(b * LLn + l) * DD + c]);
    pb[(size_t)b * DD + c] = f2b(a);
}

// ---------------- head tail: sum fc1 K-slabs + bias + tanh, fc2 + log_softmax ------------
__global__ __launch_bounds__(256) void head2_kernel(const float* __restrict__ u,
                                                    const float* __restrict__ fc1b,
                                                    const float* __restrict__ fc2w,
                                                    const float* __restrict__ fc2b,
                                                    float* __restrict__ outp) {
    int b = blockIdx.x, t = threadIdx.x;
    __shared__ float sred[4][3];
    float p0 = 0, p1 = 0, p2 = 0;
    for (int k = t; k < DD; k += 256) {
        float a = fc1b[k];
#pragma unroll
        for (int s = 0; s < 6; ++s)
            a += u[(size_t)s * 64 * DD + (size_t)b * DD + k];
        float uv = tanhf(a);
        p0 += uv * fc2w[k * 3 + 0]; p1 += uv * fc2w[k * 3 + 1]; p2 += uv * fc2w[k * 3 + 2];
    }
#pragma unroll
    for (int m = 1; m <= 32; m <<= 1) {
        p0 += __shfl_xor(p0, m, 64); p1 += __shfl_xor(p1, m, 64); p2 += __shfl_xor(p2, m, 64);
    }
    int w = t >> 6, lane = t & 63;
    if (lane == 0) { sred[w][0] = p0; sred[w][1] = p1; sred[w][2] = p2; }
    __syncthreads();
    if (t == 0) {
        float z0 = fc2b[0], z1 = fc2b[1], z2 = fc2b[2];
        for (int i = 0; i < 4; i++) { z0 += sred[i][0]; z1 += sred[i][1]; z2 += sred[i][2]; }
        float mx = fmaxf(z0, fmaxf(z1, z2));
        float lse = mx + logf(__expf(z0 - mx) + __expf(z1 - mx) + __expf(z2 - mx));
        outp[b * 3 + 0] = z0 - lse; outp[b * 3 + 1] = z1 - lse; outp[b * 3 + 2] = z2 - lse;
    }
}

// ---------------- launch ----------------
static inline char* carve(char*& p, size_t bytes) {
    char* r = p;
    p += (bytes + 255) & ~(size_t)255;
    return r;
}

extern "C" void kernel_launch(void* const* d_in, const int* in_sizes, int n_in,
                              void* d_out, int out_size, void* d_ws, size_t ws_size,
                              hipStream_t stream) {
    const float* x = (const float*)d_in[0];
    const int* ei = (const int*)d_in[1];
    const int* srcp = ei;
    const int* dstp = ei + EE;
    const float* wL[8] = {(const float*)d_in[2], (const float*)d_in[4], (const float*)d_in[6],
                          (const float*)d_in[8], (const float*)d_in[10], (const float*)d_in[12],
                          (const float*)d_in[14], (const float*)d_in[16]};
    const float* bL[8] = {(const float*)d_in[3], (const float*)d_in[5], (const float*)d_in[7],
                          (const float*)d_in[9], (const float*)d_in[11], (const float*)d_in[13],
                          (const float*)d_in[15], (const float*)d_in[17]};
    const float* atti_w = (const float*)d_in[18];
    const float* atti_b = (const float*)d_in[19];
    const float* atts_w = (const float*)d_in[20];
    const float* fc1_w = (const float*)d_in[22];
    const float* fc1_b = (const float*)d_in[23];
    const float* fc2_w = (const float*)d_in[24];
    const float* fc2_b = (const float*)d_in[25];
    float* outp = (float*)d_out;

    char* p = (char*)d_ws;
    const size_t ndb = (size_t)NN * DD * 2;
    const size_t wsz = (size_t)DD * DD * 2;
    u16* qb = (u16*)carve(p, ndb);
    u16* kb = (u16*)carve(p, ndb);
    u16* vt = (u16*)carve(p, ndb);   // V transposed [768][8192]
    u16* xb = (u16*)carve(p, ndb);   // layer1 input; reused as layer2 attn output (hp)
    u16* hb = (u16*)carve(p, ndb);   // layer1 attn output
    u16* hs = (u16*)carve(p, ndb);   // skip bf16
    u16* wtcat1 = (u16*)carve(p, wsz * 4);
    u16* wtcat2 = (u16*)carve(p, wsz * 4);
    u16* wt8 = (u16*)carve(p, wsz);
    u16* wt9 = (u16*)carve(p, wsz);
    u16* wtfc1 = (u16*)carve(p, wsz);
    u16* pb = (u16*)carve(p, (size_t)BBg * DD * 2);
    float* uu = (float*)carve(p, (size_t)BBg * DD * 4 * 6);   // 6 K-slabs of fc1 partials
    u8* cnt = (u8*)carve(p, (size_t)BBg * 128 * 128);
    float* score = (float*)carve(p, NN * 4);

    // 1) prep: zero cnt/score + convert x -> bf16
    prep_kernel<<<6144, 256, 0, stream>>>(x, xb, (unsigned int*)cnt, score);

    // 2) combo: 11 transposes + cnt histogram
    TP11 tps;
    for (int i = 0; i < 4; i++) tps.a[i] = {wL[i], wtcat1 + (size_t)i * DD * DD, 0};
    for (int i = 0; i < 4; i++) tps.a[4 + i] = {wL[4 + i], wtcat2 + (size_t)i * DD * DD, 0};
    tps.a[8] = {atti_w, wt8, 0};
    tps.a[9] = {atti_w, wt9, DD};
    tps.a[10] = {fc1_w, wtfc1, 0};
    combo_kernel<<<dim3(144, 1, 12), 256, 0, stream>>>(tps, srcp, dstp, (unsigned int*)cnt);

    dim3 gf(24, 32);           // QKVS: N=3072/128, M=8192/256
    dim3 ga(2, 2, BBg * 2);    // attention: (dst-half, head, graph x ccHalf)
    // 3-4) layer 1
    gemm256<<<gf, 512, 0, stream>>>(xb, wtcat1, bL[0], bL[1], bL[2], bL[3], qb, kb, vt, hs);
    attn_fused<<<ga, 256, 0, stream>>>(qb, kb, vt, cnt, hs, hb);
    // 5-6) layer 2
    gemm256<<<gf, 512, 0, stream>>>(hb, wtcat2, bL[4], bL[5], bL[6], bL[7], qb, kb, vt, hs);
    attn_fused<<<ga, 256, 0, stream>>>(qb, kb, vt, cnt, hs, xb);   // xb = hp bf16

    // 7) pooling scores: XC with inline Aq + fused score reduction
    gemm_xc<<<dim3(6, 64), 256, 0, stream>>>(xb, wt9, wt8, atti_b, atts_w, score);

    // 8-10) tail: pool -> bf16, fc1 K-split partials, head2 (slab-sum + tanh + fc2 + lsm)
    pool_kernel<<<dim3(3, BBg), 256, 0, stream>>>(score, xb, pb);
    fc1_kernel<<<dim3(12, 6), 256, 0, stream>>>(pb, wtfc1, uu);
    head2_kernel<<<BBg, 256, 0, stream>>>(uu, fc1_b, fc2_w, fc2_b, outp);
}

// Round 9
// 322.709 us; speedup vs baseline: 1.1386x; 1.0144x over previous
//
#include <hip/hip_runtime.h>

#define NN 8192
#define DD 768
#define EE 131072
#define BBg 64
#define LLn 128
#define CCh 384

typedef unsigned short u16;
typedef unsigned char u8;
typedef __attribute__((ext_vector_type(8))) short short8;
typedef __attribute__((ext_vector_type(4))) float f32x4;

__device__ __forceinline__ float b2f(u16 u) {
    union { unsigned int i; float f; } x; x.i = ((unsigned int)u) << 16; return x.f;
}
__device__ __forceinline__ u16 f2b(float f) {
    union { float f; unsigned int i; } x; x.f = f;
    unsigned int r = x.i + 0x7fffu + ((x.i >> 16) & 1u);
    return (u16)(r >> 16);
}
__device__ __forceinline__ void gload16(const void* g, void* l) {
    __builtin_amdgcn_global_load_lds((const __attribute__((address_space(1))) void*)g,
                                     (__attribute__((address_space(3))) void*)l, 16, 0, 0);
}

// ---------------- prep: zero cnt + zero score + f32->bf16 convert (1 dispatch) ----------------
__global__ __launch_bounds__(256) void prep_kernel(const float* __restrict__ in,
                                                   u16* __restrict__ out,
                                                   unsigned int* __restrict__ cnt32,
                                                   float* __restrict__ score) {
    int i = blockIdx.x * 256 + threadIdx.x;   // grid 6144 blocks: i < NN*DD/4
    float4 v = ((const float4*)in)[i];
    ushort4 o; o.x = f2b(v.x); o.y = f2b(v.y); o.z = f2b(v.z); o.w = f2b(v.w);
    ((ushort4*)out)[i] = o;
    if (blockIdx.x < 1024) cnt32[i] = 0;                       // 1 MB cnt
    else if (blockIdx.x < 1056) score[i - 1024 * 256] = 0.f;   // 8192 floats
}

// ---------------- combo: weight transposes (z<11) + edge histogram (z=11) ----------------
struct TP { const float* src; u16* dst; int rowOff; };
struct TP11 { TP a[11]; };

__global__ __launch_bounds__(256) void combo_kernel(TP11 args,
                                                    const int* __restrict__ srcp,
                                                    const int* __restrict__ dstp,
                                                    unsigned int* __restrict__ cnt32) {
    __shared__ float tile[64][65];
    if (blockIdx.z == 11) {
        for (int e = blockIdx.x * 256 + threadIdx.x; e < EE; e += 144 * 256) {
            int d = dstp[e], s = srcp[e];
            int g = d >> 7;
            int idx = (g << 14) + ((d & 127) << 7) + (s & 127);
            atomicAdd(&cnt32[idx >> 2], 1u << ((idx & 3) * 8));
        }
        return;
    }
    TP tp = args.a[blockIdx.z];
    int bx = blockIdx.x % 12, by = blockIdx.x / 12;
    int n0 = bx * 64, k0 = by * 64;
    int t = threadIdx.x;
    int tc = t & 63, tr = t >> 6;
#pragma unroll
    for (int i = 0; i < 16; i++)
        tile[tr + i * 4][tc] = tp.src[(size_t)(tp.rowOff + k0 + tr + i * 4) * DD + n0 + tc];
    __syncthreads();
#pragma unroll
    for (int i = 0; i < 16; i++) {
        int row = tr + i * 4;
        tp.dst[(size_t)(n0 + row) * DD + k0 + tc] = f2b(tile[tc][row]);
    }
}

// ---------------- fc1 GEMM, K-split for occupancy: grid (12 n-blocks, 6 K-chunks) ---------
__global__ __launch_bounds__(256) void fc1_kernel(const u16* __restrict__ A,
                                                  const u16* __restrict__ Wt,
                                                  float* __restrict__ uu) {
    __shared__ u16 As[64][72];
    __shared__ u16 Bs[64][72];
    const int n0 = blockIdx.x * 64;
    const int kz = blockIdx.y;
    const int t = threadIdx.x;
    const int lane = t & 63, w = t >> 6;
    const int tr = t >> 2, tc = (t & 3) * 16;
    f32x4 acc[4] = {{0,0,0,0},{0,0,0,0},{0,0,0,0},{0,0,0,0}};
    const int fRow = lane & 15;
    const int fK = (lane >> 4) * 8;

    for (int k0 = kz * 128; k0 < kz * 128 + 128; k0 += 64) {
        int4 a0 = *(const int4*)(A + (size_t)tr * DD + k0 + tc);
        int4 a1 = *(const int4*)(A + (size_t)tr * DD + k0 + tc + 8);
        int4 b0 = *(const int4*)(Wt + (size_t)(n0 + tr) * DD + k0 + tc);
        int4 b1 = *(const int4*)(Wt + (size_t)(n0 + tr) * DD + k0 + tc + 8);
        __syncthreads();
        *(int4*)&As[tr][tc] = a0; *(int4*)&As[tr][tc + 8] = a1;
        *(int4*)&Bs[tr][tc] = b0; *(int4*)&Bs[tr][tc + 8] = b1;
        __syncthreads();
#pragma unroll
        for (int s = 0; s < 2; s++) {
            short8 af = *(const short8*)&As[w * 16 + fRow][s * 32 + fK];
#pragma unroll
            for (int g = 0; g < 4; g++) {
                short8 bf = *(const short8*)&Bs[g * 16 + fRow][s * 32 + fK];
                acc[g] = __builtin_amdgcn_mfma_f32_16x16x32_bf16(af, bf, acc[g], 0, 0, 0);
            }
        }
    }
    const int colLocal = lane & 15;
    const int rowLocal = (lane >> 4) * 4;
#pragma unroll
    for (int g = 0; g < 4; g++) {
        int col = n0 + g * 16 + colLocal;
#pragma unroll
        for (int i = 0; i < 4; i++) {
            int row = w * 16 + rowLocal + i;
            uu[(size_t)kz * 64 * DD + (size_t)row * DD + col] = acc[g][i];
        }
    }
}

// ---------------- QKVS GEMM: 256x128 tile, 8 waves, 3-slab + frag-prefetch (R2 best) ------
#define SLAB 24576   // u16 per slab: A 256x64 (16384) + B 128x64 (8192) = 48 KB
__global__ __launch_bounds__(512, 2) void gemm256(const u16* __restrict__ A,
                                                  const u16* __restrict__ Wt,
                                                  const float* __restrict__ b0,
                                                  const float* __restrict__ b1,
                                                  const float* __restrict__ b2,
                                                  const float* __restrict__ b3,
                                                  u16* __restrict__ o0, u16* __restrict__ o1,
                                                  u16* __restrict__ o2, u16* __restrict__ o3) {
    __shared__ u16 smem[3 * SLAB];   // 144 KB: 3 K-tile slabs; reused by epilogue staging
    const int K = DD;
    const int t = threadIdx.x;
    const int lane = t & 63, w = t >> 6;
    const int wr = w >> 1, wc = w & 1;          // 8 waves: 4M x 2N, 64x64 C per wave
    // XCD-aware bijective swizzle (768 = 8 XCD x 96; region = 8 by x 12 bx)
    const int id = blockIdx.y * 24 + blockIdx.x;
    const int xcd = id & 7, jj = id >> 3;
    const int by = (xcd >> 1) * 8 + jj / 12;
    const int bx = (xcd & 1) * 12 + jj % 12;
    const int m0 = by * 256, n0 = bx * 128;
    const int fRow = lane & 15, fThr = lane >> 4;
    const u16* Abase = A + (size_t)m0 * K;
    const u16* Bbase = Wt + (size_t)n0 * K;

    auto stage = [&](u16* slab, int kt2) {
        const int k0 = kt2 * 64;
#pragma unroll
        for (int s = 0; s < 4; ++s) {
            int c = t + 512 * s;
            int row = c >> 3;
            int col = ((c & 7) ^ (row & 7)) * 8;
            gload16(Abase + (size_t)row * K + k0 + col, (char*)slab + (size_t)c * 16);
        }
#pragma unroll
        for (int s = 0; s < 2; ++s) {
            int c = t + 512 * s;
            int row = c >> 3;
            int col = ((c & 7) ^ (row & 7)) * 8;
            gload16(Bbase + (size_t)row * K + k0 + col, (char*)(slab + 16384) + (size_t)c * 16);
        }
    };
    auto loadFrags = [&](const u16* As, const u16* Bs, int p, short8* af, short8* bf) {
        const int cj = p * 4 + fThr;
#pragma unroll
        for (int i = 0; i < 4; ++i) {
            const int R = wr * 64 + i * 16 + fRow;
            af[i] = *(const short8*)&As[((size_t)R * 8 + (cj ^ (R & 7))) * 8];
        }
#pragma unroll
        for (int g = 0; g < 4; ++g) {
            const int Rb = wc * 64 + g * 16 + fRow;
            bf[g] = *(const short8*)&Bs[((size_t)Rb * 8 + (cj ^ (Rb & 7))) * 8];
        }
    };

    stage(smem, 0);
    stage(smem + SLAB, 1);
    asm volatile("s_waitcnt vmcnt(6)" ::: "memory");
    __builtin_amdgcn_s_barrier();

    short8 afA[4], bfA[4], afB[4], bfB[4];
    loadFrags(smem, smem + 16384, 0, afA, bfA);

    f32x4 acc[4][4] = {};
    int cur = 0;
    for (int kt = 0; kt < 12; ++kt) {
        const u16* As = smem + cur * SLAB;
        const u16* Bs = As + 16384;
        int nx = cur + 2; if (nx >= 3) nx -= 3;
        int pv = cur + 1; if (pv >= 3) pv -= 3;
        if (kt < 10) stage(smem + nx * SLAB, kt + 2);   // into slab ≡ kt-1: safe after end-of-tile barrier

        loadFrags(As, Bs, 1, afB, bfB);
        asm volatile("s_waitcnt lgkmcnt(8)" ::: "memory");
        __builtin_amdgcn_sched_barrier(0);
        __builtin_amdgcn_s_setprio(1);
#pragma unroll
        for (int i = 0; i < 4; ++i)
#pragma unroll
            for (int g = 0; g < 4; ++g)
                acc[i][g] = __builtin_amdgcn_mfma_f32_16x16x32_bf16(afA[i], bfA[g], acc[i][g], 0, 0, 0);
        __builtin_amdgcn_s_setprio(0);

        if (kt < 10) asm volatile("s_waitcnt vmcnt(6)" ::: "memory");
        else         asm volatile("s_waitcnt vmcnt(0)" ::: "memory");
        __builtin_amdgcn_s_barrier();

        if (kt < 11) {
            loadFrags(smem + pv * SLAB, smem + pv * SLAB + 16384, 0, afA, bfA);
            asm volatile("s_waitcnt lgkmcnt(8)" ::: "memory");
        } else {
            asm volatile("s_waitcnt lgkmcnt(0)" ::: "memory");
        }
        __builtin_amdgcn_sched_barrier(0);
        __builtin_amdgcn_s_setprio(1);
#pragma unroll
        for (int i = 0; i < 4; ++i)
#pragma unroll
            for (int g = 0; g < 4; ++g)
                acc[i][g] = __builtin_amdgcn_mfma_f32_16x16x32_bf16(afB[i], bfB[g], acc[i][g], 0, 0, 0);
        __builtin_amdgcn_s_setprio(0);
        __builtin_amdgcn_s_barrier();

        cur = pv;
    }

    // ---- epilogue: stage full 256x128 C tile through LDS -> coalesced ushort4 stores ----
    const int chunk = n0 / DD;
    const float* bp = (chunk == 0) ? b0 : (chunk == 1) ? b1 : (chunk == 2) ? b2 : b3;
    u16* op = (chunk == 0) ? o0 : (chunk == 1) ? o1 : (chunk == 2) ? o2 : o3;
    const int cb0 = n0 - chunk * DD;
    if (chunk == 2) {
        u16 (*Vt)[264] = (u16(*)[264])smem;
#pragma unroll
        for (int g = 0; g < 4; g++) {
            float bv = bp[cb0 + wc * 64 + g * 16 + fRow];
#pragma unroll
            for (int i = 0; i < 4; i++)
#pragma unroll
                for (int rr = 0; rr < 4; rr++)
                    Vt[wc * 64 + g * 16 + fRow][wr * 64 + i * 16 + fThr * 4 + rr] =
                        f2b(acc[i][g][rr] + bv);
        }
        __syncthreads();
#pragma unroll
        for (int ii = 0; ii < 16; ii++) {
            int c = t + 512 * ii;
            int col = c >> 6, ch = c & 63;
            *(ushort4*)(op + (size_t)(cb0 + col) * NN + m0 + ch * 4) =
                *(const ushort4*)&Vt[col][ch * 4];
        }
    } else {
        u16 (*Cs)[136] = (u16(*)[136])smem;
#pragma unroll
        for (int g = 0; g < 4; g++) {
            float bv = bp[cb0 + wc * 64 + g * 16 + fRow];
#pragma unroll
            for (int i = 0; i < 4; i++)
#pragma unroll
                for (int rr = 0; rr < 4; rr++)
                    Cs[wr * 64 + i * 16 + fThr * 4 + rr][wc * 64 + g * 16 + fRow] =
                        f2b(acc[i][g][rr] + bv);
        }
        __syncthreads();
#pragma unroll
        for (int ii = 0; ii < 16; ii++) {
            int c = t + 512 * ii;
            int row = c >> 5, ch = c & 31;
            *(ushort4*)(op + (size_t)(m0 + row) * DD + cb0 + ch * 4) =
                *(const ushort4*)&Cs[row][ch * 4];
        }
    }
}

// ---------------- XC GEMM: 128x64 tiles, 768 blocks (3/CU balanced), 25 KB LDS -----------
// Was grid(6,64)=384 blocks (1.5 per 2-slot CU -> 75% balance). Now grid(12,64): 4 waves,
// wave w owns rows [w*32,+32) x 64 cols; acc[2][4]. Aq split 4-way over K quarters.
__global__ __launch_bounds__(256) void gemm_xc(const u16* __restrict__ A,
                                               const u16* __restrict__ Wt,
                                               const u16* __restrict__ wt8,
                                               const float* __restrict__ atti_b,
                                               const float* __restrict__ atts_w,
                                               float* __restrict__ score) {
    __shared__ u16 As[128 * 64];   // 16 KB
    __shared__ u16 Bs[64 * 64];    // 8 KB
    __shared__ float aq_p[4][64];
    const int K = DD;
    const int t = threadIdx.x;
    const int lane = t & 63, w = t >> 6;
    const int n0 = blockIdx.x * 64, m0 = blockIdx.y * 128;
    const int fRow = lane & 15, fThr = lane >> 4;

    {
        int col = t & 63, kh = t >> 6;                 // kh in 0..3: 192-elem K-quarter
        const u16* xr = A + (size_t)m0 * DD + kh * 192;
        const u16* wr8 = wt8 + (size_t)(n0 + col) * DD + kh * 192;
        float s = 0.f;
#pragma unroll 8
        for (int j = 0; j < 48; j++) {
            ushort4 a4 = *(const ushort4*)(xr + j * 4);
            ushort4 b4 = *(const ushort4*)(wr8 + j * 4);
            s += b2f(a4.x) * b2f(b4.x) + b2f(a4.y) * b2f(b4.y)
               + b2f(a4.z) * b2f(b4.z) + b2f(a4.w) * b2f(b4.w);
        }
        aq_p[kh][col] = s;
    }

    f32x4 acc[2][4] = {};
    const u16* Abase = A + (size_t)m0 * K;
    const u16* Bbase = Wt + (size_t)n0 * K;
    for (int k0 = 0; k0 < K; k0 += 64) {
        __syncthreads();
#pragma unroll
        for (int i = 0; i < 4; i++) {
            int c = t + 256 * i;
            int row = c >> 3;
            int col = ((c & 7) ^ (row & 7)) * 8;
            gload16(Abase + (size_t)row * K + k0 + col, (char*)As + (size_t)c * 16);
        }
#pragma unroll
        for (int i = 0; i < 2; i++) {
            int c = t + 256 * i;
            int row = c >> 3;
            int col = ((c & 7) ^ (row & 7)) * 8;
            gload16(Bbase + (size_t)row * K + k0 + col, (char*)Bs + (size_t)c * 16);
        }
        __syncthreads();
#pragma unroll
        for (int kk = 0; kk < 64; kk += 32) {
            const int cjW = (kk >> 3) + fThr;
            short8 af[2], bf[4];
#pragma unroll
            for (int i = 0; i < 2; i++) {
                int R = w * 32 + i * 16 + fRow;
                af[i] = *(const short8*)&As[(R * 8 + (cjW ^ (R & 7))) * 8];
            }
#pragma unroll
            for (int g = 0; g < 4; g++) {
                int R = g * 16 + fRow;
                bf[g] = *(const short8*)&Bs[(R * 8 + (cjW ^ (R & 7))) * 8];
            }
#pragma unroll
            for (int i = 0; i < 2; i++)
#pragma unroll
                for (int g = 0; g < 4; g++)
                    acc[i][g] = __builtin_amdgcn_mfma_f32_16x16x32_bf16(af[i], bf[g], acc[i][g], 0, 0, 0);
        }
    }
    float rsum[2][4] = {};
#pragma unroll
    for (int g = 0; g < 4; g++) {
        int cl = g * 16 + fRow;
        int col = n0 + cl;
        float bv = atti_b[col] + aq_p[0][cl] + aq_p[1][cl] + aq_p[2][cl] + aq_p[3][cl];
        float av = atts_w[col];
#pragma unroll
        for (int i = 0; i < 2; i++)
#pragma unroll
            for (int rr = 0; rr < 4; rr++) {
                float v = fmaxf(acc[i][g][rr] + bv, 0.f);
                rsum[i][rr] += v * av;
            }
    }
#pragma unroll
    for (int i = 0; i < 2; i++)
#pragma unroll
        for (int rr = 0; rr < 4; rr++) {
            float s = rsum[i][rr];
            s += __shfl_xor(s, 1, 16); s += __shfl_xor(s, 2, 16);
            s += __shfl_xor(s, 4, 16); s += __shfl_xor(s, 8, 16);
            if (fRow == 0)
                atomicAdd(&score[m0 + w * 32 + i * 16 + fThr * 4 + rr], s);
        }
}

// ---------------- fused dense attention: LDS-staged, cc-split, T14 load/write split ------
// z = graph*2 + ccHalf; 512 blocks = 2 blocks/CU. T14: global loads for iteration k+1 are
// issued right AFTER the barrier pair of iteration k (before its MFMA cluster), so L2
// latency hides under MFMA instead of stalling at the LDS-write. Same barrier count.
__global__ __launch_bounds__(256, 2) void attn_fused(const u16* __restrict__ qb,
                                                  const u16* __restrict__ kb,
                                                  const u16* __restrict__ vT,
                                                  const u8* __restrict__ cnt,
                                                  const u16* __restrict__ hs,
                                                  u16* __restrict__ out) {
    __shared__ u16 As[64][72];
    __shared__ u16 Bs[128][72];
    __shared__ u16 Pl[64][136];
    __shared__ u16 Vt[64][136];
    const int half = blockIdx.x, hd = blockIdx.y;
    const int g = blockIdx.z >> 1, ch = blockIdx.z & 1;
    const int t = threadIdx.x;
    const int lane = t & 63, w = t >> 6;
    const int fRow = lane & 15, fThr = lane >> 4;
    const int dstBase = g * 128 + half * 64;
    const u16* Qb = qb + (size_t)dstBase * DD + hd * CCh;
    const u16* Kb = kb + (size_t)(g * 128) * DD + hd * CCh;

    f32x4 acc[8] = {};
    const int trA = t >> 2, tcA = (t & 3) * 16;
    const int trB = t >> 1, tcB = (t & 1) * 32;
    int4 a0, a1, b0, b1, b2, b3;
    auto ldK = [&](int k0) {
        a0 = *(const int4*)(Qb + (size_t)trA * DD + k0 + tcA);
        a1 = *(const int4*)(Qb + (size_t)trA * DD + k0 + tcA + 8);
        b0 = *(const int4*)(Kb + (size_t)trB * DD + k0 + tcB);
        b1 = *(const int4*)(Kb + (size_t)trB * DD + k0 + tcB + 8);
        b2 = *(const int4*)(Kb + (size_t)trB * DD + k0 + tcB + 16);
        b3 = *(const int4*)(Kb + (size_t)trB * DD + k0 + tcB + 24);
    };
    ldK(0);
    for (int k0 = 0; k0 < CCh; k0 += 64) {
        __syncthreads();
        *(int4*)&As[trA][tcA] = a0; *(int4*)&As[trA][tcA + 8] = a1;
        *(int4*)&Bs[trB][tcB] = b0; *(int4*)&Bs[trB][tcB + 8] = b1;
        *(int4*)&Bs[trB][tcB + 16] = b2; *(int4*)&Bs[trB][tcB + 24] = b3;
        __syncthreads();
        if (k0 + 64 < CCh) ldK(k0 + 64);   // T14: next loads fly under this MFMA cluster
#pragma unroll
        for (int kk = 0; kk < 64; kk += 32) {
            short8 af = *(const short8*)&As[w * 16 + fRow][kk + fThr * 8];
#pragma unroll
            for (int j = 0; j < 8; j++) {
                short8 bf = *(const short8*)&Bs[j * 16 + fRow][kk + fThr * 8];
                acc[j] = __builtin_amdgcn_mfma_f32_16x16x32_bf16(af, bf, acc[j], 0, 0, 0);
            }
        }
    }

    // preload first V chunk now: loads hide under the softmax VALU region
    const int qrow = t >> 4, qcol = (t & 15) * 8;
    int4 v0, v1, v2, v3;
    auto ldV = [&](int cc) {
        const u16* Vb = vT + (size_t)(hd * CCh + cc * 64) * NN + g * 128;
        v0 = *(const int4*)(Vb + (size_t)(qrow) * NN + qcol);
        v1 = *(const int4*)(Vb + (size_t)(qrow + 16) * NN + qcol);
        v2 = *(const int4*)(Vb + (size_t)(qrow + 32) * NN + qcol);
        v3 = *(const int4*)(Vb + (size_t)(qrow + 48) * NN + qcol);
    };
    ldV(ch * 3);

    const float scale = 0.05103103630798288f;  // 1/sqrt(384)
    const u8* cg = cnt + ((size_t)g << 14);
    const int rbase = half * 64 + w * 16 + fThr * 4;
    float pv[8][4];
#pragma unroll
    for (int i = 0; i < 4; i++) {
        float m = -3.4e38f;
#pragma unroll
        for (int j = 0; j < 8; j++) {
            float c = (float)cg[(rbase + i) * 128 + j * 16 + fRow];
            float s = acc[j][i] * scale;
            pv[j][i] = c;
            if (c > 0.f) m = fmaxf(m, s);
        }
#pragma unroll
        for (int msk = 1; msk <= 8; msk <<= 1) m = fmaxf(m, __shfl_xor(m, msk, 16));
        float sum = 0.f;
#pragma unroll
        for (int j = 0; j < 8; j++) {
            float p = (pv[j][i] > 0.f) ? pv[j][i] * __expf(acc[j][i] * scale - m) : 0.f;
            pv[j][i] = p; sum += p;
        }
#pragma unroll
        for (int msk = 1; msk <= 8; msk <<= 1) sum += __shfl_xor(sum, msk, 16);
        float inv = (sum > 0.f) ? 1.f / sum : 0.f;
#pragma unroll
        for (int j = 0; j < 8; j++)
            Pl[w * 16 + fThr * 4 + i][j * 16 + fRow] = f2b(pv[j][i] * inv);
    }

    for (int cc = ch * 3; cc < ch * 3 + 3; cc++) {
        __syncthreads();
        *(int4*)&Vt[qrow][qcol] = v0;
        *(int4*)&Vt[qrow + 16][qcol] = v1;
        *(int4*)&Vt[qrow + 32][qcol] = v2;
        *(int4*)&Vt[qrow + 48][qcol] = v3;
        __syncthreads();
        if (cc + 1 < ch * 3 + 3) ldV(cc + 1);   // T14: next V flies under PV MFMA
        f32x4 acc2[4] = {};
#pragma unroll
        for (int kk = 0; kk < 128; kk += 32) {
            short8 af = *(const short8*)&Pl[w * 16 + fRow][kk + fThr * 8];
#pragma unroll
            for (int j = 0; j < 4; j++) {
                short8 bf = *(const short8*)&Vt[j * 16 + fRow][kk + fThr * 8];
                acc2[j] = __builtin_amdgcn_mfma_f32_16x16x32_bf16(af, bf, acc2[j], 0, 0, 0);
            }
        }
#pragma unroll
        for (int j = 0; j < 4; j++) {
            int c = hd * CCh + cc * 64 + j * 16 + fRow;
#pragma unroll
            for (int i = 0; i < 4; i++) {
                int row = dstBase + w * 16 + fThr * 4 + i;
                size_t idx = (size_t)row * DD + c;
                float r = fmaxf(acc2[j][i] + b2f(hs[idx]), 0.f);
                out[idx] = f2b(r);
            }
        }
    }
}

// ---------------- per-graph softmax + weighted pool -> bf16 (192 blocks) ----------------
__global__ __launch_bounds__(256) void pool_kernel(const float* __restrict__ score,
                                                   const u16* __restrict__ hx,
                                                   u16* __restrict__ pb) {
    int chunk = blockIdx.x, b = blockIdx.y, t = threadIdx.x;
    __shared__ float sprob[LLn];
    if (t < 64) {
        float s0 = score[b * LLn + t];
        float s1 = score[b * LLn + 64 + t];
        float mx = fmaxf(s0, s1);
#pragma unroll
        for (int m = 1; m <= 32; m <<= 1) mx = fmaxf(mx, __shfl_xor(mx, m, 64));
        float e0 = __expf(s0 - mx), e1 = __expf(s1 - mx);
        float sum = e0 + e1;
#pragma unroll
        for (int m = 1; m <= 32; m <<= 1) sum += __shfl_xor(sum, m, 64);
        float inv = 1.f / sum;
        sprob[t] = e0 * inv; sprob[t + 64] = e1 * inv;
    }
    __syncthreads();
    int c = chunk * 256 + t;
    float a = 0.f;
    for (int l = 0; l < LLn; l++)
        a += sprob[l] * b2f(hx[(size_t)(b * LLn + l) * DD + c]);
    pb[(size_t)b * DD + c] = f2b(a);
}

// ---------------- head tail: sum fc1 K-slabs + bias + tanh, fc2 + log_softmax ------------
__global__ __launch_bounds__(256) void head2_kernel(const float* __restrict__ u,
                                                    const float* __restrict__ fc1b,
                                                    const float* __restrict__ fc2w,
                                                    const float* __restrict__ fc2b,
                                                    float* __restrict__ outp) {
    int b = blockIdx.x, t = threadIdx.x;
    __shared__ float sred[4][3];
    float p0 = 0, p1 = 0, p2 = 0;
    for (int k = t; k < DD; k += 256) {
        float a = fc1b[k];
#pragma unroll
        for (int s = 0; s < 6; ++s)
            a += u[(size_t)s * 64 * DD + (size_t)b * DD + k];
        float uv = tanhf(a);
        p0 += uv * fc2w[k * 3 + 0]; p1 += uv * fc2w[k * 3 + 1]; p2 += uv * fc2w[k * 3 + 2];
    }
#pragma unroll
    for (int m = 1; m <= 32; m <<= 1) {
        p0 += __shfl_xor(p0, m, 64); p1 += __shfl_xor(p1, m, 64); p2 += __shfl_xor(p2, m, 64);
    }
    int w = t >> 6, lane = t & 63;
    if (lane == 0) { sred[w][0] = p0; sred[w][1] = p1; sred[w][2] = p2; }
    __syncthreads();
    if (t == 0) {
        float z0 = fc2b[0], z1 = fc2b[1], z2 = fc2b[2];
        for (int i = 0; i < 4; i++) { z0 += sred[i][0]; z1 += sred[i][1]; z2 += sred[i][2]; }
        float mx = fmaxf(z0, fmaxf(z1, z2));
        float lse = mx + logf(__expf(z0 - mx) + __expf(z1 - mx) + __expf(z2 - mx));
        outp[b * 3 + 0] = z0 - lse; outp[b * 3 + 1] = z1 - lse; outp[b * 3 + 2] = z2 - lse;
    }
}

// ---------------- launch ----------------
static inline char* carve(char*& p, size_t bytes) {
    char* r = p;
    p += (bytes + 255) & ~(size_t)255;
    return r;
}

extern "C" void kernel_launch(void* const* d_in, const int* in_sizes, int n_in,
                              void* d_out, int out_size, void* d_ws, size_t ws_size,
                              hipStream_t stream) {
    const float* x = (const float*)d_in[0];
    const int* ei = (const int*)d_in[1];
    const int* srcp = ei;
    const int* dstp = ei + EE;
    const float* wL[8] = {(const float*)d_in[2], (const float*)d_in[4], (const float*)d_in[6],
                          (const float*)d_in[8], (const float*)d_in[10], (const float*)d_in[12],
                          (const float*)d_in[14], (const float*)d_in[16]};
    const float* bL[8] = {(const float*)d_in[3], (const float*)d_in[5], (const float*)d_in[7],
                          (const float*)d_in[9], (const float*)d_in[11], (const float*)d_in[13],
                          (const float*)d_in[15], (const float*)d_in[17]};
    const float* atti_w = (const float*)d_in[18];
    const float* atti_b = (const float*)d_in[19];
    const float* atts_w = (const float*)d_in[20];
    const float* fc1_w = (const float*)d_in[22];
    const float* fc1_b = (const float*)d_in[23];
    const float* fc2_w = (const float*)d_in[24];
    const float* fc2_b = (const float*)d_in[25];
    float* outp = (float*)d_out;

    char* p = (char*)d_ws;
    const size_t ndb = (size_t)NN * DD * 2;
    const size_t wsz = (size_t)DD * DD * 2;
    u16* qb = (u16*)carve(p, ndb);
    u16* kb = (u16*)carve(p, ndb);
    u16* vt = (u16*)carve(p, ndb);   // V transposed [768][8192]
    u16* xb = (u16*)carve(p, ndb);   // layer1 input; reused as layer2 attn output (hp)
    u16* hb = (u16*)carve(p, ndb);   // layer1 attn output
    u16* hs = (u16*)carve(p, ndb);   // skip bf16
    u16* wtcat1 = (u16*)carve(p, wsz * 4);
    u16* wtcat2 = (u16*)carve(p, wsz * 4);
    u16* wt8 = (u16*)carve(p, wsz);
    u16* wt9 = (u16*)carve(p, wsz);
    u16* wtfc1 = (u16*)carve(p, wsz);
    u16* pb = (u16*)carve(p, (size_t)BBg * DD * 2);
    float* uu = (float*)carve(p, (size_t)BBg * DD * 4 * 6);   // 6 K-slabs of fc1 partials
    u8* cnt = (u8*)carve(p, (size_t)BBg * 128 * 128);
    float* score = (float*)carve(p, NN * 4);

    // 1) prep: zero cnt/score + convert x -> bf16
    prep_kernel<<<6144, 256, 0, stream>>>(x, xb, (unsigned int*)cnt, score);

    // 2) combo: 11 transposes + cnt histogram
    TP11 tps;
    for (int i = 0; i < 4; i++) tps.a[i] = {wL[i], wtcat1 + (size_t)i * DD * DD, 0};
    for (int i = 0; i < 4; i++) tps.a[4 + i] = {wL[4 + i], wtcat2 + (size_t)i * DD * DD, 0};
    tps.a[8] = {atti_w, wt8, 0};
    tps.a[9] = {atti_w, wt9, DD};
    tps.a[10] = {fc1_w, wtfc1, 0};
    combo_kernel<<<dim3(144, 1, 12), 256, 0, stream>>>(tps, srcp, dstp, (unsigned int*)cnt);

    dim3 gf(24, 32);           // QKVS: N=3072/128, M=8192/256
    dim3 ga(2, 2, BBg * 2);    // attention: (dst-half, head, graph x ccHalf)
    // 3-4) layer 1
    gemm256<<<gf, 512, 0, stream>>>(xb, wtcat1, bL[0], bL[1], bL[2], bL[3], qb, kb, vt, hs);
    attn_fused<<<ga, 256, 0, stream>>>(qb, kb, vt, cnt, hs, hb);
    // 5-6) layer 2
    gemm256<<<gf, 512, 0, stream>>>(hb, wtcat2, bL[4], bL[5], bL[6], bL[7], qb, kb, vt, hs);
    attn_fused<<<ga, 256, 0, stream>>>(qb, kb, vt, cnt, hs, xb);   // xb = hp bf16

    // 7) pooling scores: XC 128x64 tiles, 768 blocks (3/CU balanced)
    gemm_xc<<<dim3(12, 64), 256, 0, stream>>>(xb, wt9, wt8, atti_b, atts_w, score);

    // 8-10) tail: pool -> bf16, fc1 K-split partials, head2 (slab-sum + tanh + fc2 + lsm)
    pool_kernel<<<dim3(3, BBg), 256, 0, stream>>>(score, xb, pb);
    fc1_kernel<<<dim3(12, 6), 256, 0, stream>>>(pb, wtfc1, uu);
    head2_kernel<<<BBg, 256, 0, stream>>>(uu, fc1_b, fc2_w, fc2_b, outp);
}

// Round 10
// 310.793 us; speedup vs baseline: 1.1823x; 1.0383x over previous
//
#include <hip/hip_runtime.h>

#define NN 8192
#define DD 768
#define EE 131072
#define BBg 64
#define LLn 128
#define CCh 384

typedef unsigned short u16;
typedef unsigned char u8;
typedef __attribute__((ext_vector_type(8))) short short8;
typedef __attribute__((ext_vector_type(4))) float f32x4;

__device__ __forceinline__ float b2f(u16 u) {
    union { unsigned int i; float f; } x; x.i = ((unsigned int)u) << 16; return x.f;
}
__device__ __forceinline__ u16 f2b(float f) {
    union { float f; unsigned int i; } x; x.f = f;
    unsigned int r = x.i + 0x7fffu + ((x.i >> 16) & 1u);
    return (u16)(r >> 16);
}
__device__ __forceinline__ void gload16(const void* g, void* l) {
    __builtin_amdgcn_global_load_lds((const __attribute__((address_space(1))) void*)g,
                                     (__attribute__((address_space(3))) void*)l, 16, 0, 0);
}

// ---------------- prep: zero cnt + zero score + f32->bf16 convert (1 dispatch) ----------------
__global__ __launch_bounds__(256) void prep_kernel(const float* __restrict__ in,
                                                   u16* __restrict__ out,
                                                   unsigned int* __restrict__ cnt32,
                                                   float* __restrict__ score) {
    int i = blockIdx.x * 256 + threadIdx.x;   // grid 6144 blocks: i < NN*DD/4
    float4 v = ((const float4*)in)[i];
    ushort4 o; o.x = f2b(v.x); o.y = f2b(v.y); o.z = f2b(v.z); o.w = f2b(v.w);
    ((ushort4*)out)[i] = o;
    if (blockIdx.x < 1024) cnt32[i] = 0;                       // 1 MB cnt
    else if (blockIdx.x < 1056) score[i - 1024 * 256] = 0.f;   // 8192 floats
}

// ---------------- combo: weight transposes (z<11) + edge histogram (z=11) ----------------
struct TP { const float* src; u16* dst; int rowOff; };
struct TP11 { TP a[11]; };

__global__ __launch_bounds__(256) void combo_kernel(TP11 args,
                                                    const int* __restrict__ srcp,
                                                    const int* __restrict__ dstp,
                                                    unsigned int* __restrict__ cnt32) {
    __shared__ float tile[64][65];
    if (blockIdx.z == 11) {
        for (int e = blockIdx.x * 256 + threadIdx.x; e < EE; e += 144 * 256) {
            int d = dstp[e], s = srcp[e];
            int g = d >> 7;
            int idx = (g << 14) + ((d & 127) << 7) + (s & 127);
            atomicAdd(&cnt32[idx >> 2], 1u << ((idx & 3) * 8));
        }
        return;
    }
    TP tp = args.a[blockIdx.z];
    int bx = blockIdx.x % 12, by = blockIdx.x / 12;
    int n0 = bx * 64, k0 = by * 64;
    int t = threadIdx.x;
    int tc = t & 63, tr = t >> 6;
#pragma unroll
    for (int i = 0; i < 16; i++)
        tile[tr + i * 4][tc] = tp.src[(size_t)(tp.rowOff + k0 + tr + i * 4) * DD + n0 + tc];
    __syncthreads();
#pragma unroll
    for (int i = 0; i < 16; i++) {
        int row = tr + i * 4;
        tp.dst[(size_t)(n0 + row) * DD + k0 + tc] = f2b(tile[tc][row]);
    }
}

// ---------------- fc1 GEMM, K-split for occupancy: grid (12 n-blocks, 6 K-chunks) ---------
__global__ __launch_bounds__(256) void fc1_kernel(const u16* __restrict__ A,
                                                  const u16* __restrict__ Wt,
                                                  float* __restrict__ uu) {
    __shared__ u16 As[64][72];
    __shared__ u16 Bs[64][72];
    const int n0 = blockIdx.x * 64;
    const int kz = blockIdx.y;
    const int t = threadIdx.x;
    const int lane = t & 63, w = t >> 6;
    const int tr = t >> 2, tc = (t & 3) * 16;
    f32x4 acc[4] = {{0,0,0,0},{0,0,0,0},{0,0,0,0},{0,0,0,0}};
    const int fRow = lane & 15;
    const int fK = (lane >> 4) * 8;

    for (int k0 = kz * 128; k0 < kz * 128 + 128; k0 += 64) {
        int4 a0 = *(const int4*)(A + (size_t)tr * DD + k0 + tc);
        int4 a1 = *(const int4*)(A + (size_t)tr * DD + k0 + tc + 8);
        int4 b0 = *(const int4*)(Wt + (size_t)(n0 + tr) * DD + k0 + tc);
        int4 b1 = *(const int4*)(Wt + (size_t)(n0 + tr) * DD + k0 + tc + 8);
        __syncthreads();
        *(int4*)&As[tr][tc] = a0; *(int4*)&As[tr][tc + 8] = a1;
        *(int4*)&Bs[tr][tc] = b0; *(int4*)&Bs[tr][tc + 8] = b1;
        __syncthreads();
#pragma unroll
        for (int s = 0; s < 2; s++) {
            short8 af = *(const short8*)&As[w * 16 + fRow][s * 32 + fK];
#pragma unroll
            for (int g = 0; g < 4; g++) {
                short8 bf = *(const short8*)&Bs[g * 16 + fRow][s * 32 + fK];
                acc[g] = __builtin_amdgcn_mfma_f32_16x16x32_bf16(af, bf, acc[g], 0, 0, 0);
            }
        }
    }
    const int colLocal = lane & 15;
    const int rowLocal = (lane >> 4) * 4;
#pragma unroll
    for (int g = 0; g < 4; g++) {
        int col = n0 + g * 16 + colLocal;
#pragma unroll
        for (int i = 0; i < 4; i++) {
            int row = w * 16 + rowLocal + i;
            uu[(size_t)kz * 64 * DD + (size_t)row * DD + col] = acc[g][i];
        }
    }
}

// ---------------- QKVS GEMM: 256x128 tile, 8 waves, 3-slab + frag-prefetch (R2 best) ------
#define SLAB 24576   // u16 per slab: A 256x64 (16384) + B 128x64 (8192) = 48 KB
__global__ __launch_bounds__(512, 2) void gemm256(const u16* __restrict__ A,
                                                  const u16* __restrict__ Wt,
                                                  const float* __restrict__ b0,
                                                  const float* __restrict__ b1,
                                                  const float* __restrict__ b2,
                                                  const float* __restrict__ b3,
                                                  u16* __restrict__ o0, u16* __restrict__ o1,
                                                  u16* __restrict__ o2, u16* __restrict__ o3) {
    __shared__ u16 smem[3 * SLAB];   // 144 KB: 3 K-tile slabs; reused by epilogue staging
    const int K = DD;
    const int t = threadIdx.x;
    const int lane = t & 63, w = t >> 6;
    const int wr = w >> 1, wc = w & 1;          // 8 waves: 4M x 2N, 64x64 C per wave
    // XCD-aware bijective swizzle (768 = 8 XCD x 96; region = 8 by x 12 bx)
    const int id = blockIdx.y * 24 + blockIdx.x;
    const int xcd = id & 7, jj = id >> 3;
    const int by = (xcd >> 1) * 8 + jj / 12;
    const int bx = (xcd & 1) * 12 + jj % 12;
    const int m0 = by * 256, n0 = bx * 128;
    const int fRow = lane & 15, fThr = lane >> 4;
    const u16* Abase = A + (size_t)m0 * K;
    const u16* Bbase = Wt + (size_t)n0 * K;

    auto stage = [&](u16* slab, int kt2) {
        const int k0 = kt2 * 64;
#pragma unroll
        for (int s = 0; s < 4; ++s) {
            int c = t + 512 * s;
            int row = c >> 3;
            int col = ((c & 7) ^ (row & 7)) * 8;
            gload16(Abase + (size_t)row * K + k0 + col, (char*)slab + (size_t)c * 16);
        }
#pragma unroll
        for (int s = 0; s < 2; ++s) {
            int c = t + 512 * s;
            int row = c >> 3;
            int col = ((c & 7) ^ (row & 7)) * 8;
            gload16(Bbase + (size_t)row * K + k0 + col, (char*)(slab + 16384) + (size_t)c * 16);
        }
    };
    auto loadFrags = [&](const u16* As, const u16* Bs, int p, short8* af, short8* bf) {
        const int cj = p * 4 + fThr;
#pragma unroll
        for (int i = 0; i < 4; ++i) {
            const int R = wr * 64 + i * 16 + fRow;
            af[i] = *(const short8*)&As[((size_t)R * 8 + (cj ^ (R & 7))) * 8];
        }
#pragma unroll
        for (int g = 0; g < 4; ++g) {
            const int Rb = wc * 64 + g * 16 + fRow;
            bf[g] = *(const short8*)&Bs[((size_t)Rb * 8 + (cj ^ (Rb & 7))) * 8];
        }
    };

    stage(smem, 0);
    stage(smem + SLAB, 1);
    asm volatile("s_waitcnt vmcnt(6)" ::: "memory");
    __builtin_amdgcn_s_barrier();

    short8 afA[4], bfA[4], afB[4], bfB[4];
    loadFrags(smem, smem + 16384, 0, afA, bfA);

    f32x4 acc[4][4] = {};
    int cur = 0;
    for (int kt = 0; kt < 12; ++kt) {
        const u16* As = smem + cur * SLAB;
        const u16* Bs = As + 16384;
        int nx = cur + 2; if (nx >= 3) nx -= 3;
        int pv = cur + 1; if (pv >= 3) pv -= 3;
        if (kt < 10) stage(smem + nx * SLAB, kt + 2);   // into slab ≡ kt-1: safe after end-of-tile barrier

        loadFrags(As, Bs, 1, afB, bfB);
        asm volatile("s_waitcnt lgkmcnt(8)" ::: "memory");
        __builtin_amdgcn_sched_barrier(0);
        __builtin_amdgcn_s_setprio(1);
#pragma unroll
        for (int i = 0; i < 4; ++i)
#pragma unroll
            for (int g = 0; g < 4; ++g)
                acc[i][g] = __builtin_amdgcn_mfma_f32_16x16x32_bf16(afA[i], bfA[g], acc[i][g], 0, 0, 0);
        __builtin_amdgcn_s_setprio(0);

        if (kt < 10) asm volatile("s_waitcnt vmcnt(6)" ::: "memory");
        else         asm volatile("s_waitcnt vmcnt(0)" ::: "memory");
        __builtin_amdgcn_s_barrier();

        if (kt < 11) {
            loadFrags(smem + pv * SLAB, smem + pv * SLAB + 16384, 0, afA, bfA);
            asm volatile("s_waitcnt lgkmcnt(8)" ::: "memory");
        } else {
            asm volatile("s_waitcnt lgkmcnt(0)" ::: "memory");
        }
        __builtin_amdgcn_sched_barrier(0);
        __builtin_amdgcn_s_setprio(1);
#pragma unroll
        for (int i = 0; i < 4; ++i)
#pragma unroll
            for (int g = 0; g < 4; ++g)
                acc[i][g] = __builtin_amdgcn_mfma_f32_16x16x32_bf16(afB[i], bfB[g], acc[i][g], 0, 0, 0);
        __builtin_amdgcn_s_setprio(0);
        __builtin_amdgcn_s_barrier();

        cur = pv;
    }

    // ---- epilogue: stage full 256x128 C tile through LDS -> coalesced ushort4 stores ----
    const int chunk = n0 / DD;
    const float* bp = (chunk == 0) ? b0 : (chunk == 1) ? b1 : (chunk == 2) ? b2 : b3;
    u16* op = (chunk == 0) ? o0 : (chunk == 1) ? o1 : (chunk == 2) ? o2 : o3;
    const int cb0 = n0 - chunk * DD;
    if (chunk == 2) {
        u16 (*Vt)[264] = (u16(*)[264])smem;
#pragma unroll
        for (int g = 0; g < 4; g++) {
            float bv = bp[cb0 + wc * 64 + g * 16 + fRow];
#pragma unroll
            for (int i = 0; i < 4; i++)
#pragma unroll
                for (int rr = 0; rr < 4; rr++)
                    Vt[wc * 64 + g * 16 + fRow][wr * 64 + i * 16 + fThr * 4 + rr] =
                        f2b(acc[i][g][rr] + bv);
        }
        __syncthreads();
#pragma unroll
        for (int ii = 0; ii < 16; ii++) {
            int c = t + 512 * ii;
            int col = c >> 6, ch = c & 63;
            *(ushort4*)(op + (size_t)(cb0 + col) * NN + m0 + ch * 4) =
                *(const ushort4*)&Vt[col][ch * 4];
        }
    } else {
        u16 (*Cs)[136] = (u16(*)[136])smem;
#pragma unroll
        for (int g = 0; g < 4; g++) {
            float bv = bp[cb0 + wc * 64 + g * 16 + fRow];
#pragma unroll
            for (int i = 0; i < 4; i++)
#pragma unroll
                for (int rr = 0; rr < 4; rr++)
                    Cs[wr * 64 + i * 16 + fThr * 4 + rr][wc * 64 + g * 16 + fRow] =
                        f2b(acc[i][g][rr] + bv);
        }
        __syncthreads();
#pragma unroll
        for (int ii = 0; ii < 16; ii++) {
            int c = t + 512 * ii;
            int row = c >> 5, ch = c & 31;
            *(ushort4*)(op + (size_t)(m0 + row) * DD + cb0 + ch * 4) =
                *(const ushort4*)&Cs[row][ch * 4];
        }
    }
}

// ---------------- XC GEMM: 128x64 tiles, 768 blocks, XCD-grouped m-panels ----------------
// 1D grid 768. Decode co-locates the 12 blocks sharing one 196KB A-panel on ONE XCD
// (per-XCD working set: 8 panels x 196KB + B 1.2MB + wt8 ~= 4MB L2). mg=(id&7)*8+((id>>3)&7),
// bx=id>>6: bijective, all 12 blocks of a panel share id%8 -> same XCD under round-robin.
__global__ __launch_bounds__(256) void gemm_xc(const u16* __restrict__ A,
                                               const u16* __restrict__ Wt,
                                               const u16* __restrict__ wt8,
                                               const float* __restrict__ atti_b,
                                               const float* __restrict__ atts_w,
                                               float* __restrict__ score) {
    __shared__ u16 As[128 * 64];   // 16 KB
    __shared__ u16 Bs[64 * 64];    // 8 KB
    __shared__ float aq_p[4][64];
    const int K = DD;
    const int t = threadIdx.x;
    const int lane = t & 63, w = t >> 6;
    const int id = blockIdx.x;
    const int mg = (id & 7) * 8 + ((id >> 3) & 7);   // m-panel 0..63
    const int bxx = id >> 6;                         // 0..11
    const int n0 = bxx * 64, m0 = mg * 128;
    const int fRow = lane & 15, fThr = lane >> 4;

    {
        int col = t & 63, kh = t >> 6;                 // kh in 0..3: 192-elem K-quarter
        const u16* xr = A + (size_t)m0 * DD + kh * 192;
        const u16* wr8 = wt8 + (size_t)(n0 + col) * DD + kh * 192;
        float s = 0.f;
#pragma unroll 8
        for (int j = 0; j < 48; j++) {
            ushort4 a4 = *(const ushort4*)(xr + j * 4);
            ushort4 b4 = *(const ushort4*)(wr8 + j * 4);
            s += b2f(a4.x) * b2f(b4.x) + b2f(a4.y) * b2f(b4.y)
               + b2f(a4.z) * b2f(b4.z) + b2f(a4.w) * b2f(b4.w);
        }
        aq_p[kh][col] = s;
    }

    f32x4 acc[2][4] = {};
    const u16* Abase = A + (size_t)m0 * K;
    const u16* Bbase = Wt + (size_t)n0 * K;
    for (int k0 = 0; k0 < K; k0 += 64) {
        __syncthreads();
#pragma unroll
        for (int i = 0; i < 4; i++) {
            int c = t + 256 * i;
            int row = c >> 3;
            int col = ((c & 7) ^ (row & 7)) * 8;
            gload16(Abase + (size_t)row * K + k0 + col, (char*)As + (size_t)c * 16);
        }
#pragma unroll
        for (int i = 0; i < 2; i++) {
            int c = t + 256 * i;
            int row = c >> 3;
            int col = ((c & 7) ^ (row & 7)) * 8;
            gload16(Bbase + (size_t)row * K + k0 + col, (char*)Bs + (size_t)c * 16);
        }
        __syncthreads();
#pragma unroll
        for (int kk = 0; kk < 64; kk += 32) {
            const int cjW = (kk >> 3) + fThr;
            short8 af[2], bf[4];
#pragma unroll
            for (int i = 0; i < 2; i++) {
                int R = w * 32 + i * 16 + fRow;
                af[i] = *(const short8*)&As[(R * 8 + (cjW ^ (R & 7))) * 8];
            }
#pragma unroll
            for (int g = 0; g < 4; g++) {
                int R = g * 16 + fRow;
                bf[g] = *(const short8*)&Bs[(R * 8 + (cjW ^ (R & 7))) * 8];
            }
#pragma unroll
            for (int i = 0; i < 2; i++)
#pragma unroll
                for (int g = 0; g < 4; g++)
                    acc[i][g] = __builtin_amdgcn_mfma_f32_16x16x32_bf16(af[i], bf[g], acc[i][g], 0, 0, 0);
        }
    }
    float rsum[2][4] = {};
#pragma unroll
    for (int g = 0; g < 4; g++) {
        int cl = g * 16 + fRow;
        int col = n0 + cl;
        float bv = atti_b[col] + aq_p[0][cl] + aq_p[1][cl] + aq_p[2][cl] + aq_p[3][cl];
        float av = atts_w[col];
#pragma unroll
        for (int i = 0; i < 2; i++)
#pragma unroll
            for (int rr = 0; rr < 4; rr++) {
                float v = fmaxf(acc[i][g][rr] + bv, 0.f);
                rsum[i][rr] += v * av;
            }
    }
#pragma unroll
    for (int i = 0; i < 2; i++)
#pragma unroll
        for (int rr = 0; rr < 4; rr++) {
            float s = rsum[i][rr];
            s += __shfl_xor(s, 1, 16); s += __shfl_xor(s, 2, 16);
            s += __shfl_xor(s, 4, 16); s += __shfl_xor(s, 8, 16);
            if (fRow == 0)
                atomicAdd(&score[m0 + w * 32 + i * 16 + fThr * 4 + rr], s);
        }
}

// ---------------- fused dense attention: LDS-staged, cc-split, T14, XCD-grouped ----------
// 1D grid 512. Decode: g=(id&7)*8+((id>>3)&7); (half,hd,ch)=id>>6. All 8 blocks sharing
// one graph's K/Q/V/cnt (~3.2MB) get the same id%8 -> same XCD -> L2-served re-reads
// (they were round-robin scattered before: every re-read went to L3).
__global__ __launch_bounds__(256, 2) void attn_fused(const u16* __restrict__ qb,
                                                  const u16* __restrict__ kb,
                                                  const u16* __restrict__ vT,
                                                  const u8* __restrict__ cnt,
                                                  const u16* __restrict__ hs,
                                                  u16* __restrict__ out) {
    __shared__ u16 As[64][72];
    __shared__ u16 Bs[128][72];
    __shared__ u16 Pl[64][136];
    __shared__ u16 Vt[64][136];
    const int id = blockIdx.x;
    const int g = (id & 7) * 8 + ((id >> 3) & 7);
    const int rest = id >> 6;
    const int half = rest & 1, hd = (rest >> 1) & 1, ch = rest >> 2;
    const int t = threadIdx.x;
    const int lane = t & 63, w = t >> 6;
    const int fRow = lane & 15, fThr = lane >> 4;
    const int dstBase = g * 128 + half * 64;
    const u16* Qb = qb + (size_t)dstBase * DD + hd * CCh;
    const u16* Kb = kb + (size_t)(g * 128) * DD + hd * CCh;

    f32x4 acc[8] = {};
    const int trA = t >> 2, tcA = (t & 3) * 16;
    const int trB = t >> 1, tcB = (t & 1) * 32;
    int4 a0, a1, b0, b1, b2, b3;
    auto ldK = [&](int k0) {
        a0 = *(const int4*)(Qb + (size_t)trA * DD + k0 + tcA);
        a1 = *(const int4*)(Qb + (size_t)trA * DD + k0 + tcA + 8);
        b0 = *(const int4*)(Kb + (size_t)trB * DD + k0 + tcB);
        b1 = *(const int4*)(Kb + (size_t)trB * DD + k0 + tcB + 8);
        b2 = *(const int4*)(Kb + (size_t)trB * DD + k0 + tcB + 16);
        b3 = *(const int4*)(Kb + (size_t)trB * DD + k0 + tcB + 24);
    };
    ldK(0);
    for (int k0 = 0; k0 < CCh; k0 += 64) {
        __syncthreads();
        *(int4*)&As[trA][tcA] = a0; *(int4*)&As[trA][tcA + 8] = a1;
        *(int4*)&Bs[trB][tcB] = b0; *(int4*)&Bs[trB][tcB + 8] = b1;
        *(int4*)&Bs[trB][tcB + 16] = b2; *(int4*)&Bs[trB][tcB + 24] = b3;
        __syncthreads();
        if (k0 + 64 < CCh) ldK(k0 + 64);   // T14: next loads fly under this MFMA cluster
#pragma unroll
        for (int kk = 0; kk < 64; kk += 32) {
            short8 af = *(const short8*)&As[w * 16 + fRow][kk + fThr * 8];
#pragma unroll
            for (int j = 0; j < 8; j++) {
                short8 bf = *(const short8*)&Bs[j * 16 + fRow][kk + fThr * 8];
                acc[j] = __builtin_amdgcn_mfma_f32_16x16x32_bf16(af, bf, acc[j], 0, 0, 0);
            }
        }
    }

    // preload first V chunk now: loads hide under the softmax VALU region
    const int qrow = t >> 4, qcol = (t & 15) * 8;
    int4 v0, v1, v2, v3;
    auto ldV = [&](int cc) {
        const u16* Vb = vT + (size_t)(hd * CCh + cc * 64) * NN + g * 128;
        v0 = *(const int4*)(Vb + (size_t)(qrow) * NN + qcol);
        v1 = *(const int4*)(Vb + (size_t)(qrow + 16) * NN + qcol);
        v2 = *(const int4*)(Vb + (size_t)(qrow + 32) * NN + qcol);
        v3 = *(const int4*)(Vb + (size_t)(qrow + 48) * NN + qcol);
    };
    ldV(ch * 3);

    const float scale = 0.05103103630798288f;  // 1/sqrt(384)
    const u8* cg = cnt + ((size_t)g << 14);
    const int rbase = half * 64 + w * 16 + fThr * 4;
    float pv[8][4];
#pragma unroll
    for (int i = 0; i < 4; i++) {
        float m = -3.4e38f;
#pragma unroll
        for (int j = 0; j < 8; j++) {
            float c = (float)cg[(rbase + i) * 128 + j * 16 + fRow];
            float s = acc[j][i] * scale;
            pv[j][i] = c;
            if (c > 0.f) m = fmaxf(m, s);
        }
#pragma unroll
        for (int msk = 1; msk <= 8; msk <<= 1) m = fmaxf(m, __shfl_xor(m, msk, 16));
        float sum = 0.f;
#pragma unroll
        for (int j = 0; j < 8; j++) {
            float p = (pv[j][i] > 0.f) ? pv[j][i] * __expf(acc[j][i] * scale - m) : 0.f;
            pv[j][i] = p; sum += p;
        }
#pragma unroll
        for (int msk = 1; msk <= 8; msk <<= 1) sum += __shfl_xor(sum, msk, 16);
        float inv = (sum > 0.f) ? 1.f / sum : 0.f;
#pragma unroll
        for (int j = 0; j < 8; j++)
            Pl[w * 16 + fThr * 4 + i][j * 16 + fRow] = f2b(pv[j][i] * inv);
    }

    for (int cc = ch * 3; cc < ch * 3 + 3; cc++) {
        __syncthreads();
        *(int4*)&Vt[qrow][qcol] = v0;
        *(int4*)&Vt[qrow + 16][qcol] = v1;
        *(int4*)&Vt[qrow + 32][qcol] = v2;
        *(int4*)&Vt[qrow + 48][qcol] = v3;
        __syncthreads();
        if (cc + 1 < ch * 3 + 3) ldV(cc + 1);   // T14: next V flies under PV MFMA
        f32x4 acc2[4] = {};
#pragma unroll
        for (int kk = 0; kk < 128; kk += 32) {
            short8 af = *(const short8*)&Pl[w * 16 + fRow][kk + fThr * 8];
#pragma unroll
            for (int j = 0; j < 4; j++) {
                short8 bf = *(const short8*)&Vt[j * 16 + fRow][kk + fThr * 8];
                acc2[j] = __builtin_amdgcn_mfma_f32_16x16x32_bf16(af, bf, acc2[j], 0, 0, 0);
            }
        }
#pragma unroll
        for (int j = 0; j < 4; j++) {
            int c = hd * CCh + cc * 64 + j * 16 + fRow;
#pragma unroll
            for (int i = 0; i < 4; i++) {
                int row = dstBase + w * 16 + fThr * 4 + i;
                size_t idx = (size_t)row * DD + c;
                float r = fmaxf(acc2[j][i] + b2f(hs[idx]), 0.f);
                out[idx] = f2b(r);
            }
        }
    }
}

// ---------------- per-graph softmax + weighted pool -> bf16 (192 blocks) ----------------
__global__ __launch_bounds__(256) void pool_kernel(const float* __restrict__ score,
                                                   const u16* __restrict__ hx,
                                                   u16* __restrict__ pb) {
    int chunk = blockIdx.x, b = blockIdx.y, t = threadIdx.x;
    __shared__ float sprob[LLn];
    if (t < 64) {
        float s0 = score[b * LLn + t];
        float s1 = score[b * LLn + 64 + t];
        float mx = fmaxf(s0, s1);
#pragma unroll
        for (int m = 1; m <= 32; m <<= 1) mx = fmaxf(mx, __shfl_xor(mx, m, 64));
        float e0 = __expf(s0 - mx), e1 = __expf(s1 - mx);
        float sum = e0 + e1;
#pragma unroll
        for (int m = 1; m <= 32; m <<= 1) sum += __shfl_xor(sum, m, 64);
        float inv = 1.f / sum;
        sprob[t] = e0 * inv; sprob[t + 64] = e1 * inv;
    }
    __syncthreads();
    int c = chunk * 256 + t;
    float a = 0.f;
    for (int l = 0; l < LLn; l++)
        a += sprob[l] * b2f(hx[(size_t)(b * LLn + l) * DD + c]);
    pb[(size_t)b * DD + c] = f2b(a);
}

// ---------------- head tail: sum fc1 K-slabs + bias + tanh, fc2 + log_softmax ------------
__global__ __launch_bounds__(256) void head2_kernel(const float* __restrict__ u,
                                                    const float* __restrict__ fc1b,
                                                    const float* __restrict__ fc2w,
                                                    const float* __restrict__ fc2b,
                                                    float* __restrict__ outp) {
    int b = blockIdx.x, t = threadIdx.x;
    __shared__ float sred[4][3];
    float p0 = 0, p1 = 0, p2 = 0;
    for (int k = t; k < DD; k += 256) {
        float a = fc1b[k];
#pragma unroll
        for (int s = 0; s < 6; ++s)
            a += u[(size_t)s * 64 * DD + (size_t)b * DD + k];
        float uv = tanhf(a);
        p0 += uv * fc2w[k * 3 + 0]; p1 += uv * fc2w[k * 3 + 1]; p2 += uv * fc2w[k * 3 + 2];
    }
#pragma unroll
    for (int m = 1; m <= 32; m <<= 1) {
        p0 += __shfl_xor(p0, m, 64); p1 += __shfl_xor(p1, m, 64); p2 += __shfl_xor(p2, m, 64);
    }
    int w = t >> 6, lane = t & 63;
    if (lane == 0) { sred[w][0] = p0; sred[w][1] = p1; sred[w][2] = p2; }
    __syncthreads();
    if (t == 0) {
        float z0 = fc2b[0], z1 = fc2b[1], z2 = fc2b[2];
        for (int i = 0; i < 4; i++) { z0 += sred[i][0]; z1 += sred[i][1]; z2 += sred[i][2]; }
        float mx = fmaxf(z0, fmaxf(z1, z2));
        float lse = mx + logf(__expf(z0 - mx) + __expf(z1 - mx) + __expf(z2 - mx));
        outp[b * 3 + 0] = z0 - lse; outp[b * 3 + 1] = z1 - lse; outp[b * 3 + 2] = z2 - lse;
    }
}

// ---------------- launch ----------------
static inline char* carve(char*& p, size_t bytes) {
    char* r = p;
    p += (bytes + 255) & ~(size_t)255;
    return r;
}

extern "C" void kernel_launch(void* const* d_in, const int* in_sizes, int n_in,
                              void* d_out, int out_size, void* d_ws, size_t ws_size,
                              hipStream_t stream) {
    const float* x = (const float*)d_in[0];
    const int* ei = (const int*)d_in[1];
    const int* srcp = ei;
    const int* dstp = ei + EE;
    const float* wL[8] = {(const float*)d_in[2], (const float*)d_in[4], (const float*)d_in[6],
                          (const float*)d_in[8], (const float*)d_in[10], (const float*)d_in[12],
                          (const float*)d_in[14], (const float*)d_in[16]};
    const float* bL[8] = {(const float*)d_in[3], (const float*)d_in[5], (const float*)d_in[7],
                          (const float*)d_in[9], (const float*)d_in[11], (const float*)d_in[13],
                          (const float*)d_in[15], (const float*)d_in[17]};
    const float* atti_w = (const float*)d_in[18];
    const float* atti_b = (const float*)d_in[19];
    const float* atts_w = (const float*)d_in[20];
    const float* fc1_w = (const float*)d_in[22];
    const float* fc1_b = (const float*)d_in[23];
    const float* fc2_w = (const float*)d_in[24];
    const float* fc2_b = (const float*)d_in[25];
    float* outp = (float*)d_out;

    char* p = (char*)d_ws;
    const size_t ndb = (size_t)NN * DD * 2;
    const size_t wsz = (size_t)DD * DD * 2;
    u16* qb = (u16*)carve(p, ndb);
    u16* kb = (u16*)carve(p, ndb);
    u16* vt = (u16*)carve(p, ndb);   // V transposed [768][8192]
    u16* xb = (u16*)carve(p, ndb);   // layer1 input; reused as layer2 attn output (hp)
    u16* hb = (u16*)carve(p, ndb);   // layer1 attn output
    u16* hs = (u16*)carve(p, ndb);   // skip bf16
    u16* wtcat1 = (u16*)carve(p, wsz * 4);
    u16* wtcat2 = (u16*)carve(p, wsz * 4);
    u16* wt8 = (u16*)carve(p, wsz);
    u16* wt9 = (u16*)carve(p, wsz);
    u16* wtfc1 = (u16*)carve(p, wsz);
    u16* pb = (u16*)carve(p, (size_t)BBg * DD * 2);
    float* uu = (float*)carve(p, (size_t)BBg * DD * 4 * 6);   // 6 K-slabs of fc1 partials
    u8* cnt = (u8*)carve(p, (size_t)BBg * 128 * 128);
    float* score = (float*)carve(p, NN * 4);

    // 1) prep: zero cnt/score + convert x -> bf16
    prep_kernel<<<6144, 256, 0, stream>>>(x, xb, (unsigned int*)cnt, score);

    // 2) combo: 11 transposes + cnt histogram
    TP11 tps;
    for (int i = 0; i < 4; i++) tps.a[i] = {wL[i], wtcat1 + (size_t)i * DD * DD, 0};
    for (int i = 0; i < 4; i++) tps.a[4 + i] = {wL[4 + i], wtcat2 + (size_t)i * DD * DD, 0};
    tps.a[8] = {atti_w, wt8, 0};
    tps.a[9] = {atti_w, wt9, DD};
    tps.a[10] = {fc1_w, wtfc1, 0};
    combo_kernel<<<dim3(144, 1, 12), 256, 0, stream>>>(tps, srcp, dstp, (unsigned int*)cnt);

    dim3 gf(24, 32);           // QKVS: N=3072/128, M=8192/256
    // 3-4) layer 1
    gemm256<<<gf, 512, 0, stream>>>(xb, wtcat1, bL[0], bL[1], bL[2], bL[3], qb, kb, vt, hs);
    attn_fused<<<512, 256, 0, stream>>>(qb, kb, vt, cnt, hs, hb);
    // 5-6) layer 2
    gemm256<<<gf, 512, 0, stream>>>(hb, wtcat2, bL[4], bL[5], bL[6], bL[7], qb, kb, vt, hs);
    attn_fused<<<512, 256, 0, stream>>>(qb, kb, vt, cnt, hs, xb);   // xb = hp bf16

    // 7) pooling scores: XC 128x64 tiles, 768 blocks, XCD-grouped m-panels
    gemm_xc<<<768, 256, 0, stream>>>(xb, wt9, wt8, atti_b, atts_w, score);

    // 8-10) tail: pool -> bf16, fc1 K-split partials, head2 (slab-sum + tanh + fc2 + lsm)
    pool_kernel<<<dim3(3, BBg), 256, 0, stream>>>(score, xb, pb);
    fc1_kernel<<<dim3(12, 6), 256, 0, stream>>>(pb, wtfc1, uu);
    head2_kernel<<<BBg, 256, 0, stream>>>(uu, fc1_b, fc2_w, fc2_b, outp);
}

// Round 11
// 304.964 us; speedup vs baseline: 1.2049x; 1.0191x over previous
//
#include <hip/hip_runtime.h>

#define NN 8192
#define DD 768
#define EE 131072
#define BBg 64
#define LLn 128
#define CCh 384

typedef unsigned short u16;
typedef unsigned char u8;
typedef __attribute__((ext_vector_type(8))) short short8;
typedef __attribute__((ext_vector_type(4))) float f32x4;

__device__ __forceinline__ float b2f(u16 u) {
    union { unsigned int i; float f; } x; x.i = ((unsigned int)u) << 16; return x.f;
}
__device__ __forceinline__ u16 f2b(float f) {
    union { float f; unsigned int i; } x; x.f = f;
    unsigned int r = x.i + 0x7fffu + ((x.i >> 16) & 1u);
    return (u16)(r >> 16);
}
__device__ __forceinline__ void gload16(const void* g, void* l) {
    __builtin_amdgcn_global_load_lds((const __attribute__((address_space(1))) void*)g,
                                     (__attribute__((address_space(3))) void*)l, 16, 0, 0);
}

// ---------------- prep: zero cnt + zero score + f32->bf16 convert (1 dispatch) ----------------
__global__ __launch_bounds__(256) void prep_kernel(const float* __restrict__ in,
                                                   u16* __restrict__ out,
                                                   unsigned int* __restrict__ cnt32,
                                                   float* __restrict__ score) {
    int i = blockIdx.x * 256 + threadIdx.x;   // grid 6144 blocks: i < NN*DD/4
    float4 v = ((const float4*)in)[i];
    ushort4 o; o.x = f2b(v.x); o.y = f2b(v.y); o.z = f2b(v.z); o.w = f2b(v.w);
    ((ushort4*)out)[i] = o;
    if (blockIdx.x < 1024) cnt32[i] = 0;                       // 1 MB cnt
    else if (blockIdx.x < 1056) score[i - 1024 * 256] = 0.f;   // 8192 floats
}

// ---------------- combo: weight transposes (z<11) + edge histogram (z=11) ----------------
struct TP { const float* src; u16* dst; int rowOff; };
struct TP11 { TP a[11]; };

__global__ __launch_bounds__(256) void combo_kernel(TP11 args,
                                                    const int* __restrict__ srcp,
                                                    const int* __restrict__ dstp,
                                                    unsigned int* __restrict__ cnt32) {
    __shared__ float tile[64][65];
    if (blockIdx.z == 11) {
        for (int e = blockIdx.x * 256 + threadIdx.x; e < EE; e += 144 * 256) {
            int d = dstp[e], s = srcp[e];
            int g = d >> 7;
            int idx = (g << 14) + ((d & 127) << 7) + (s & 127);
            atomicAdd(&cnt32[idx >> 2], 1u << ((idx & 3) * 8));
        }
        return;
    }
    TP tp = args.a[blockIdx.z];
    int bx = blockIdx.x % 12, by = blockIdx.x / 12;
    int n0 = bx * 64, k0 = by * 64;
    int t = threadIdx.x;
    int tc = t & 63, tr = t >> 6;
#pragma unroll
    for (int i = 0; i < 16; i++)
        tile[tr + i * 4][tc] = tp.src[(size_t)(tp.rowOff + k0 + tr + i * 4) * DD + n0 + tc];
    __syncthreads();
#pragma unroll
    for (int i = 0; i < 16; i++) {
        int row = tr + i * 4;
        tp.dst[(size_t)(n0 + row) * DD + k0 + tc] = f2b(tile[tc][row]);
    }
}

// ---------------- fc1 GEMM, K-split for occupancy: grid (12 n-blocks, 6 K-chunks) ---------
__global__ __launch_bounds__(256) void fc1_kernel(const u16* __restrict__ A,
                                                  const u16* __restrict__ Wt,
                                                  float* __restrict__ uu) {
    __shared__ u16 As[64][72];
    __shared__ u16 Bs[64][72];
    const int n0 = blockIdx.x * 64;
    const int kz = blockIdx.y;
    const int t = threadIdx.x;
    const int lane = t & 63, w = t >> 6;
    const int tr = t >> 2, tc = (t & 3) * 16;
    f32x4 acc[4] = {{0,0,0,0},{0,0,0,0},{0,0,0,0},{0,0,0,0}};
    const int fRow = lane & 15;
    const int fK = (lane >> 4) * 8;

    for (int k0 = kz * 128; k0 < kz * 128 + 128; k0 += 64) {
        int4 a0 = *(const int4*)(A + (size_t)tr * DD + k0 + tc);
        int4 a1 = *(const int4*)(A + (size_t)tr * DD + k0 + tc + 8);
        int4 b0 = *(const int4*)(Wt + (size_t)(n0 + tr) * DD + k0 + tc);
        int4 b1 = *(const int4*)(Wt + (size_t)(n0 + tr) * DD + k0 + tc + 8);
        __syncthreads();
        *(int4*)&As[tr][tc] = a0; *(int4*)&As[tr][tc + 8] = a1;
        *(int4*)&Bs[tr][tc] = b0; *(int4*)&Bs[tr][tc + 8] = b1;
        __syncthreads();
#pragma unroll
        for (int s = 0; s < 2; s++) {
            short8 af = *(const short8*)&As[w * 16 + fRow][s * 32 + fK];
#pragma unroll
            for (int g = 0; g < 4; g++) {
                short8 bf = *(const short8*)&Bs[g * 16 + fRow][s * 32 + fK];
                acc[g] = __builtin_amdgcn_mfma_f32_16x16x32_bf16(af, bf, acc[g], 0, 0, 0);
            }
        }
    }
    const int colLocal = lane & 15;
    const int rowLocal = (lane >> 4) * 4;
#pragma unroll
    for (int g = 0; g < 4; g++) {
        int col = n0 + g * 16 + colLocal;
#pragma unroll
        for (int i = 0; i < 4; i++) {
            int row = w * 16 + rowLocal + i;
            uu[(size_t)kz * 64 * DD + (size_t)row * DD + col] = acc[g][i];
        }
    }
}

// ---------------- QKVS GEMM: 256x128 tile, 8 waves, 3-slab + frag-prefetch (R2 best) ------
#define SLAB 24576   // u16 per slab: A 256x64 (16384) + B 128x64 (8192) = 48 KB
__global__ __launch_bounds__(512, 2) void gemm256(const u16* __restrict__ A,
                                                  const u16* __restrict__ Wt,
                                                  const float* __restrict__ b0,
                                                  const float* __restrict__ b1,
                                                  const float* __restrict__ b2,
                                                  const float* __restrict__ b3,
                                                  u16* __restrict__ o0, u16* __restrict__ o1,
                                                  u16* __restrict__ o2, u16* __restrict__ o3) {
    __shared__ u16 smem[3 * SLAB];   // 144 KB: 3 K-tile slabs; reused by epilogue staging
    const int K = DD;
    const int t = threadIdx.x;
    const int lane = t & 63, w = t >> 6;
    const int wr = w >> 1, wc = w & 1;          // 8 waves: 4M x 2N, 64x64 C per wave
    // XCD-aware bijective swizzle (768 = 8 XCD x 96; region = 8 by x 12 bx)
    const int id = blockIdx.y * 24 + blockIdx.x;
    const int xcd = id & 7, jj = id >> 3;
    const int by = (xcd >> 1) * 8 + jj / 12;
    const int bx = (xcd & 1) * 12 + jj % 12;
    const int m0 = by * 256, n0 = bx * 128;
    const int fRow = lane & 15, fThr = lane >> 4;
    const u16* Abase = A + (size_t)m0 * K;
    const u16* Bbase = Wt + (size_t)n0 * K;

    auto stage = [&](u16* slab, int kt2) {
        const int k0 = kt2 * 64;
#pragma unroll
        for (int s = 0; s < 4; ++s) {
            int c = t + 512 * s;
            int row = c >> 3;
            int col = ((c & 7) ^ (row & 7)) * 8;
            gload16(Abase + (size_t)row * K + k0 + col, (char*)slab + (size_t)c * 16);
        }
#pragma unroll
        for (int s = 0; s < 2; ++s) {
            int c = t + 512 * s;
            int row = c >> 3;
            int col = ((c & 7) ^ (row & 7)) * 8;
            gload16(Bbase + (size_t)row * K + k0 + col, (char*)(slab + 16384) + (size_t)c * 16);
        }
    };
    auto loadFrags = [&](const u16* As, const u16* Bs, int p, short8* af, short8* bf) {
        const int cj = p * 4 + fThr;
#pragma unroll
        for (int i = 0; i < 4; ++i) {
            const int R = wr * 64 + i * 16 + fRow;
            af[i] = *(const short8*)&As[((size_t)R * 8 + (cj ^ (R & 7))) * 8];
        }
#pragma unroll
        for (int g = 0; g < 4; ++g) {
            const int Rb = wc * 64 + g * 16 + fRow;
            bf[g] = *(const short8*)&Bs[((size_t)Rb * 8 + (cj ^ (Rb & 7))) * 8];
        }
    };

    stage(smem, 0);
    stage(smem + SLAB, 1);
    asm volatile("s_waitcnt vmcnt(6)" ::: "memory");
    __builtin_amdgcn_s_barrier();

    short8 afA[4], bfA[4], afB[4], bfB[4];
    loadFrags(smem, smem + 16384, 0, afA, bfA);

    f32x4 acc[4][4] = {};
    int cur = 0;
    for (int kt = 0; kt < 12; ++kt) {
        const u16* As = smem + cur * SLAB;
        const u16* Bs = As + 16384;
        int nx = cur + 2; if (nx >= 3) nx -= 3;
        int pv = cur + 1; if (pv >= 3) pv -= 3;
        if (kt < 10) stage(smem + nx * SLAB, kt + 2);   // into slab ≡ kt-1: safe after end-of-tile barrier

        loadFrags(As, Bs, 1, afB, bfB);
        asm volatile("s_waitcnt lgkmcnt(8)" ::: "memory");
        __builtin_amdgcn_sched_barrier(0);
        __builtin_amdgcn_s_setprio(1);
#pragma unroll
        for (int i = 0; i < 4; ++i)
#pragma unroll
            for (int g = 0; g < 4; ++g)
                acc[i][g] = __builtin_amdgcn_mfma_f32_16x16x32_bf16(afA[i], bfA[g], acc[i][g], 0, 0, 0);
        __builtin_amdgcn_s_setprio(0);

        if (kt < 10) asm volatile("s_waitcnt vmcnt(6)" ::: "memory");
        else         asm volatile("s_waitcnt vmcnt(0)" ::: "memory");
        __builtin_amdgcn_s_barrier();

        if (kt < 11) {
            loadFrags(smem + pv * SLAB, smem + pv * SLAB + 16384, 0, afA, bfA);
            asm volatile("s_waitcnt lgkmcnt(8)" ::: "memory");
        } else {
            asm volatile("s_waitcnt lgkmcnt(0)" ::: "memory");
        }
        __builtin_amdgcn_sched_barrier(0);
        __builtin_amdgcn_s_setprio(1);
#pragma unroll
        for (int i = 0; i < 4; ++i)
#pragma unroll
            for (int g = 0; g < 4; ++g)
                acc[i][g] = __builtin_amdgcn_mfma_f32_16x16x32_bf16(afB[i], bfB[g], acc[i][g], 0, 0, 0);
        __builtin_amdgcn_s_setprio(0);
        __builtin_amdgcn_s_barrier();

        cur = pv;
    }

    // ---- epilogue: stage full 256x128 C tile through LDS -> coalesced ushort4 stores ----
    const int chunk = n0 / DD;
    const float* bp = (chunk == 0) ? b0 : (chunk == 1) ? b1 : (chunk == 2) ? b2 : b3;
    u16* op = (chunk == 0) ? o0 : (chunk == 1) ? o1 : (chunk == 2) ? o2 : o3;
    const int cb0 = n0 - chunk * DD;
    if (chunk == 2) {
        u16 (*Vt)[264] = (u16(*)[264])smem;
#pragma unroll
        for (int g = 0; g < 4; g++) {
            float bv = bp[cb0 + wc * 64 + g * 16 + fRow];
#pragma unroll
            for (int i = 0; i < 4; i++)
#pragma unroll
                for (int rr = 0; rr < 4; rr++)
                    Vt[wc * 64 + g * 16 + fRow][wr * 64 + i * 16 + fThr * 4 + rr] =
                        f2b(acc[i][g][rr] + bv);
        }
        __syncthreads();
#pragma unroll
        for (int ii = 0; ii < 16; ii++) {
            int c = t + 512 * ii;
            int col = c >> 6, ch = c & 63;
            *(ushort4*)(op + (size_t)(cb0 + col) * NN + m0 + ch * 4) =
                *(const ushort4*)&Vt[col][ch * 4];
        }
    } else {
        u16 (*Cs)[136] = (u16(*)[136])smem;
#pragma unroll
        for (int g = 0; g < 4; g++) {
            float bv = bp[cb0 + wc * 64 + g * 16 + fRow];
#pragma unroll
            for (int i = 0; i < 4; i++)
#pragma unroll
                for (int rr = 0; rr < 4; rr++)
                    Cs[wr * 64 + i * 16 + fThr * 4 + rr][wc * 64 + g * 16 + fRow] =
                        f2b(acc[i][g][rr] + bv);
        }
        __syncthreads();
#pragma unroll
        for (int ii = 0; ii < 16; ii++) {
            int c = t + 512 * ii;
            int row = c >> 5, ch = c & 31;
            *(ushort4*)(op + (size_t)(m0 + row) * DD + cb0 + ch * 4) =
                *(const ushort4*)&Cs[row][ch * 4];
        }
    }
}

// ---------------- XC GEMM: 128x64 tiles, 768 blocks, XCD-grouped m-panels ----------------
__global__ __launch_bounds__(256) void gemm_xc(const u16* __restrict__ A,
                                               const u16* __restrict__ Wt,
                                               const u16* __restrict__ wt8,
                                               const float* __restrict__ atti_b,
                                               const float* __restrict__ atts_w,
                                               float* __restrict__ score) {
    __shared__ u16 As[128 * 64];   // 16 KB
    __shared__ u16 Bs[64 * 64];    // 8 KB
    __shared__ float aq_p[4][64];
    const int K = DD;
    const int t = threadIdx.x;
    const int lane = t & 63, w = t >> 6;
    const int id = blockIdx.x;
    const int mg = (id & 7) * 8 + ((id >> 3) & 7);   // m-panel 0..63
    const int bxx = id >> 6;                         // 0..11
    const int n0 = bxx * 64, m0 = mg * 128;
    const int fRow = lane & 15, fThr = lane >> 4;

    {
        int col = t & 63, kh = t >> 6;                 // kh in 0..3: 192-elem K-quarter
        const u16* xr = A + (size_t)m0 * DD + kh * 192;
        const u16* wr8 = wt8 + (size_t)(n0 + col) * DD + kh * 192;
        float s = 0.f;
#pragma unroll 8
        for (int j = 0; j < 48; j++) {
            ushort4 a4 = *(const ushort4*)(xr + j * 4);
            ushort4 b4 = *(const ushort4*)(wr8 + j * 4);
            s += b2f(a4.x) * b2f(b4.x) + b2f(a4.y) * b2f(b4.y)
               + b2f(a4.z) * b2f(b4.z) + b2f(a4.w) * b2f(b4.w);
        }
        aq_p[kh][col] = s;
    }

    f32x4 acc[2][4] = {};
    const u16* Abase = A + (size_t)m0 * K;
    const u16* Bbase = Wt + (size_t)n0 * K;
    for (int k0 = 0; k0 < K; k0 += 64) {
        __syncthreads();
#pragma unroll
        for (int i = 0; i < 4; i++) {
            int c = t + 256 * i;
            int row = c >> 3;
            int col = ((c & 7) ^ (row & 7)) * 8;
            gload16(Abase + (size_t)row * K + k0 + col, (char*)As + (size_t)c * 16);
        }
#pragma unroll
        for (int i = 0; i < 2; i++) {
            int c = t + 256 * i;
            int row = c >> 3;
            int col = ((c & 7) ^ (row & 7)) * 8;
            gload16(Bbase + (size_t)row * K + k0 + col, (char*)Bs + (size_t)c * 16);
        }
        __syncthreads();
#pragma unroll
        for (int kk = 0; kk < 64; kk += 32) {
            const int cjW = (kk >> 3) + fThr;
            short8 af[2], bf[4];
#pragma unroll
            for (int i = 0; i < 2; i++) {
                int R = w * 32 + i * 16 + fRow;
                af[i] = *(const short8*)&As[(R * 8 + (cjW ^ (R & 7))) * 8];
            }
#pragma unroll
            for (int g = 0; g < 4; g++) {
                int R = g * 16 + fRow;
                bf[g] = *(const short8*)&Bs[(R * 8 + (cjW ^ (R & 7))) * 8];
            }
#pragma unroll
            for (int i = 0; i < 2; i++)
#pragma unroll
                for (int g = 0; g < 4; g++)
                    acc[i][g] = __builtin_amdgcn_mfma_f32_16x16x32_bf16(af[i], bf[g], acc[i][g], 0, 0, 0);
        }
    }
    float rsum[2][4] = {};
#pragma unroll
    for (int g = 0; g < 4; g++) {
        int cl = g * 16 + fRow;
        int col = n0 + cl;
        float bv = atti_b[col] + aq_p[0][cl] + aq_p[1][cl] + aq_p[2][cl] + aq_p[3][cl];
        float av = atts_w[col];
#pragma unroll
        for (int i = 0; i < 2; i++)
#pragma unroll
            for (int rr = 0; rr < 4; rr++) {
                float v = fmaxf(acc[i][g][rr] + bv, 0.f);
                rsum[i][rr] += v * av;
            }
    }
#pragma unroll
    for (int i = 0; i < 2; i++)
#pragma unroll
        for (int rr = 0; rr < 4; rr++) {
            float s = rsum[i][rr];
            s += __shfl_xor(s, 1, 16); s += __shfl_xor(s, 2, 16);
            s += __shfl_xor(s, 4, 16); s += __shfl_xor(s, 8, 16);
            if (fRow == 0)
                atomicAdd(&score[m0 + w * 32 + i * 16 + fThr * 4 + rr], s);
        }
}

// ---------------- fused dense attention: Q-in-regs, 52KB LDS -> 3 blocks/CU --------------
// As buffer dropped: Q frags are per-wave private, loaded ONCE from global (12 short8/lane,
// one-time gather hidden under K staging; unlike R7, K/V stay LDS-staged per iteration).
// LDS = Bs 18.4K + Pl 17.4K + Vt 17.4K = 52.0 KB -> 3 blocks/CU (was 2), 3 waves/SIMD.
// Keeps: cc-split, T14 prefetch of K and V, XCD grouping (g=(id&7)*8+((id>>3)&7)).
__global__ __launch_bounds__(256, 3) void attn_fused(const u16* __restrict__ qb,
                                                  const u16* __restrict__ kb,
                                                  const u16* __restrict__ vT,
                                                  const u8* __restrict__ cnt,
                                                  const u16* __restrict__ hs,
                                                  u16* __restrict__ out) {
    __shared__ u16 Bs[128][72];
    __shared__ u16 Pl[64][136];
    __shared__ u16 Vt[64][136];
    const int id = blockIdx.x;
    const int g = (id & 7) * 8 + ((id >> 3) & 7);
    const int rest = id >> 6;
    const int half = rest & 1, hd = (rest >> 1) & 1, ch = rest >> 2;
    const int t = threadIdx.x;
    const int lane = t & 63, w = t >> 6;
    const int fRow = lane & 15, fThr = lane >> 4;
    const int dstBase = g * 128 + half * 64;
    const u16* Qb = qb + (size_t)dstBase * DD + hd * CCh;
    const u16* Kb = kb + (size_t)(g * 128) * DD + hd * CCh;

    // K staging (coalesced) with T14 prefetch
    const int trB = t >> 1, tcB = (t & 1) * 32;
    int4 b0, b1, b2, b3;
    auto ldK = [&](int k0) {
        b0 = *(const int4*)(Kb + (size_t)trB * DD + k0 + tcB);
        b1 = *(const int4*)(Kb + (size_t)trB * DD + k0 + tcB + 8);
        b2 = *(const int4*)(Kb + (size_t)trB * DD + k0 + tcB + 16);
        b3 = *(const int4*)(Kb + (size_t)trB * DD + k0 + tcB + 24);
    };
    ldK(0);

    // Q fragments in registers: lane handles Q row (w*16+fRow), k = s*32 + fThr*8
    const u16* Qrow = Qb + (size_t)(w * 16 + fRow) * DD + fThr * 8;
    short8 qf[12];
#pragma unroll
    for (int s = 0; s < 12; ++s) qf[s] = *(const short8*)(Qrow + s * 32);

    f32x4 acc[8] = {};
    for (int k0 = 0; k0 < CCh; k0 += 64) {
        __syncthreads();
        *(int4*)&Bs[trB][tcB] = b0; *(int4*)&Bs[trB][tcB + 8] = b1;
        *(int4*)&Bs[trB][tcB + 16] = b2; *(int4*)&Bs[trB][tcB + 24] = b3;
        __syncthreads();
        if (k0 + 64 < CCh) ldK(k0 + 64);   // T14: next loads fly under this MFMA cluster
#pragma unroll
        for (int kk = 0; kk < 64; kk += 32) {
            short8 af = qf[(k0 >> 5) + (kk >> 5)];
#pragma unroll
            for (int j = 0; j < 8; j++) {
                short8 bf = *(const short8*)&Bs[j * 16 + fRow][kk + fThr * 8];
                acc[j] = __builtin_amdgcn_mfma_f32_16x16x32_bf16(af, bf, acc[j], 0, 0, 0);
            }
        }
    }

    // preload first V chunk now: loads hide under the softmax VALU region
    const int qrow = t >> 4, qcol = (t & 15) * 8;
    int4 v0, v1, v2, v3;
    auto ldV = [&](int cc) {
        const u16* Vb = vT + (size_t)(hd * CCh + cc * 64) * NN + g * 128;
        v0 = *(const int4*)(Vb + (size_t)(qrow) * NN + qcol);
        v1 = *(const int4*)(Vb + (size_t)(qrow + 16) * NN + qcol);
        v2 = *(const int4*)(Vb + (size_t)(qrow + 32) * NN + qcol);
        v3 = *(const int4*)(Vb + (size_t)(qrow + 48) * NN + qcol);
    };
    ldV(ch * 3);

    const float scale = 0.05103103630798288f;  // 1/sqrt(384)
    const u8* cg = cnt + ((size_t)g << 14);
    const int rbase = half * 64 + w * 16 + fThr * 4;
    float pv[8][4];
#pragma unroll
    for (int i = 0; i < 4; i++) {
        float m = -3.4e38f;
#pragma unroll
        for (int j = 0; j < 8; j++) {
            float c = (float)cg[(rbase + i) * 128 + j * 16 + fRow];
            float s = acc[j][i] * scale;
            pv[j][i] = c;
            if (c > 0.f) m = fmaxf(m, s);
        }
#pragma unroll
        for (int msk = 1; msk <= 8; msk <<= 1) m = fmaxf(m, __shfl_xor(m, msk, 16));
        float sum = 0.f;
#pragma unroll
        for (int j = 0; j < 8; j++) {
            float p = (pv[j][i] > 0.f) ? pv[j][i] * __expf(acc[j][i] * scale - m) : 0.f;
            pv[j][i] = p; sum += p;
        }
#pragma unroll
        for (int msk = 1; msk <= 8; msk <<= 1) sum += __shfl_xor(sum, msk, 16);
        float inv = (sum > 0.f) ? 1.f / sum : 0.f;
#pragma unroll
        for (int j = 0; j < 8; j++)
            Pl[w * 16 + fThr * 4 + i][j * 16 + fRow] = f2b(pv[j][i] * inv);
    }

    for (int cc = ch * 3; cc < ch * 3 + 3; cc++) {
        __syncthreads();
        *(int4*)&Vt[qrow][qcol] = v0;
        *(int4*)&Vt[qrow + 16][qcol] = v1;
        *(int4*)&Vt[qrow + 32][qcol] = v2;
        *(int4*)&Vt[qrow + 48][qcol] = v3;
        __syncthreads();
        if (cc + 1 < ch * 3 + 3) ldV(cc + 1);   // T14: next V flies under PV MFMA
        f32x4 acc2[4] = {};
#pragma unroll
        for (int kk = 0; kk < 128; kk += 32) {
            short8 af = *(const short8*)&Pl[w * 16 + fRow][kk + fThr * 8];
#pragma unroll
            for (int j = 0; j < 4; j++) {
                short8 bf = *(const short8*)&Vt[j * 16 + fRow][kk + fThr * 8];
                acc2[j] = __builtin_amdgcn_mfma_f32_16x16x32_bf16(af, bf, acc2[j], 0, 0, 0);
            }
        }
#pragma unroll
        for (int j = 0; j < 4; j++) {
            int c = hd * CCh + cc * 64 + j * 16 + fRow;
#pragma unroll
            for (int i = 0; i < 4; i++) {
                int row = dstBase + w * 16 + fThr * 4 + i;
                size_t idx = (size_t)row * DD + c;
                float r = fmaxf(acc2[j][i] + b2f(hs[idx]), 0.f);
                out[idx] = f2b(r);
            }
        }
    }
}

// ---------------- per-graph softmax + weighted pool -> bf16 (192 blocks) ----------------
__global__ __launch_bounds__(256) void pool_kernel(const float* __restrict__ score,
                                                   const u16* __restrict__ hx,
                                                   u16* __restrict__ pb) {
    int chunk = blockIdx.x, b = blockIdx.y, t = threadIdx.x;
    __shared__ float sprob[LLn];
    if (t < 64) {
        float s0 = score[b * LLn + t];
        float s1 = score[b * LLn + 64 + t];
        float mx = fmaxf(s0, s1);
#pragma unroll
        for (int m = 1; m <= 32; m <<= 1) mx = fmaxf(mx, __shfl_xor(mx, m, 64));
        float e0 = __expf(s0 - mx), e1 = __expf(s1 - mx);
        float sum = e0 + e1;
#pragma unroll
        for (int m = 1; m <= 32; m <<= 1) sum += __shfl_xor(sum, m, 64);
        float inv = 1.f / sum;
        sprob[t] = e0 * inv; sprob[t + 64] = e1 * inv;
    }
    __syncthreads();
    int c = chunk * 256 + t;
    float a = 0.f;
    for (int l = 0; l < LLn; l++)
        a += sprob[l] * b2f(hx[(size_t)(b * LLn + l) * DD + c]);
    pb[(size_t)b * DD + c] = f2b(a);
}

// ---------------- head tail: sum fc1 K-slabs + bias + tanh, fc2 + log_softmax ------------
__global__ __launch_bounds__(256) void head2_kernel(const float* __restrict__ u,
                                                    const float* __restrict__ fc1b,
                                                    const float* __restrict__ fc2w,
                                                    const float* __restrict__ fc2b,
                                                    float* __restrict__ outp) {
    int b = blockIdx.x, t = threadIdx.x;
    __shared__ float sred[4][3];
    float p0 = 0, p1 = 0, p2 = 0;
    for (int k = t; k < DD; k += 256) {
        float a = fc1b[k];
#pragma unroll
        for (int s = 0; s < 6; ++s)
            a += u[(size_t)s * 64 * DD + (size_t)b * DD + k];
        float uv = tanhf(a);
        p0 += uv * fc2w[k * 3 + 0]; p1 += uv * fc2w[k * 3 + 1]; p2 += uv * fc2w[k * 3 + 2];
    }
#pragma unroll
    for (int m = 1; m <= 32; m <<= 1) {
        p0 += __shfl_xor(p0, m, 64); p1 += __shfl_xor(p1, m, 64); p2 += __shfl_xor(p2, m, 64);
    }
    int w = t >> 6, lane = t & 63;
    if (lane == 0) { sred[w][0] = p0; sred[w][1] = p1; sred[w][2] = p2; }
    __syncthreads();
    if (t == 0) {
        float z0 = fc2b[0], z1 = fc2b[1], z2 = fc2b[2];
        for (int i = 0; i < 4; i++) { z0 += sred[i][0]; z1 += sred[i][1]; z2 += sred[i][2]; }
        float mx = fmaxf(z0, fmaxf(z1, z2));
        float lse = mx + logf(__expf(z0 - mx) + __expf(z1 - mx) + __expf(z2 - mx));
        outp[b * 3 + 0] = z0 - lse; outp[b * 3 + 1] = z1 - lse; outp[b * 3 + 2] = z2 - lse;
    }
}

// ---------------- launch ----------------
static inline char* carve(char*& p, size_t bytes) {
    char* r = p;
    p += (bytes + 255) & ~(size_t)255;
    return r;
}

extern "C" void kernel_launch(void* const* d_in, const int* in_sizes, int n_in,
                              void* d_out, int out_size, void* d_ws, size_t ws_size,
                              hipStream_t stream) {
    const float* x = (const float*)d_in[0];
    const int* ei = (const int*)d_in[1];
    const int* srcp = ei;
    const int* dstp = ei + EE;
    const float* wL[8] = {(const float*)d_in[2], (const float*)d_in[4], (const float*)d_in[6],
                          (const float*)d_in[8], (const float*)d_in[10], (const float*)d_in[12],
                          (const float*)d_in[14], (const float*)d_in[16]};
    const float* bL[8] = {(const float*)d_in[3], (const float*)d_in[5], (const float*)d_in[7],
                          (const float*)d_in[9], (const float*)d_in[11], (const float*)d_in[13],
                          (const float*)d_in[15], (const float*)d_in[17]};
    const float* atti_w = (const float*)d_in[18];
    const float* atti_b = (const float*)d_in[19];
    const float* atts_w = (const float*)d_in[20];
    const float* fc1_w = (const float*)d_in[22];
    const float* fc1_b = (const float*)d_in[23];
    const float* fc2_w = (const float*)d_in[24];
    const float* fc2_b = (const float*)d_in[25];
    float* outp = (float*)d_out;

    char* p = (char*)d_ws;
    const size_t ndb = (size_t)NN * DD * 2;
    const size_t wsz = (size_t)DD * DD * 2;
    u16* qb = (u16*)carve(p, ndb);
    u16* kb = (u16*)carve(p, ndb);
    u16* vt = (u16*)carve(p, ndb);   // V transposed [768][8192]
    u16* xb = (u16*)carve(p, ndb);   // layer1 input; reused as layer2 attn output (hp)
    u16* hb = (u16*)carve(p, ndb);   // layer1 attn output
    u16* hs = (u16*)carve(p, ndb);   // skip bf16
    u16* wtcat1 = (u16*)carve(p, wsz * 4);
    u16* wtcat2 = (u16*)carve(p, wsz * 4);
    u16* wt8 = (u16*)carve(p, wsz);
    u16* wt9 = (u16*)carve(p, wsz);
    u16* wtfc1 = (u16*)carve(p, wsz);
    u16* pb = (u16*)carve(p, (size_t)BBg * DD * 2);
    float* uu = (float*)carve(p, (size_t)BBg * DD * 4 * 6);   // 6 K-slabs of fc1 partials
    u8* cnt = (u8*)carve(p, (size_t)BBg * 128 * 128);
    float* score = (float*)carve(p, NN * 4);

    // 1) prep: zero cnt/score + convert x -> bf16
    prep_kernel<<<6144, 256, 0, stream>>>(x, xb, (unsigned int*)cnt, score);

    // 2) combo: 11 transposes + cnt histogram
    TP11 tps;
    for (int i = 0; i < 4; i++) tps.a[i] = {wL[i], wtcat1 + (size_t)i * DD * DD, 0};
    for (int i = 0; i < 4; i++) tps.a[4 + i] = {wL[4 + i], wtcat2 + (size_t)i * DD * DD, 0};
    tps.a[8] = {atti_w, wt8, 0};
    tps.a[9] = {atti_w, wt9, DD};
    tps.a[10] = {fc1_w, wtfc1, 0};
    combo_kernel<<<dim3(144, 1, 12), 256, 0, stream>>>(tps, srcp, dstp, (unsigned int*)cnt);

    dim3 gf(24, 32);           // QKVS: N=3072/128, M=8192/256
    // 3-4) layer 1
    gemm256<<<gf, 512, 0, stream>>>(xb, wtcat1, bL[0], bL[1], bL[2], bL[3], qb, kb, vt, hs);
    attn_fused<<<512, 256, 0, stream>>>(qb, kb, vt, cnt, hs, hb);
    // 5-6) layer 2
    gemm256<<<gf, 512, 0, stream>>>(hb, wtcat2, bL[4], bL[5], bL[6], bL[7], qb, kb, vt, hs);
    attn_fused<<<512, 256, 0, stream>>>(qb, kb, vt, cnt, hs, xb);   // xb = hp bf16

    // 7) pooling scores: XC 128x64 tiles, 768 blocks, XCD-grouped m-panels
    gemm_xc<<<768, 256, 0, stream>>>(xb, wt9, wt8, atti_b, atts_w, score);

    // 8-10) tail: pool -> bf16, fc1 K-split partials, head2 (slab-sum + tanh + fc2 + lsm)
    pool_kernel<<<dim3(3, BBg), 256, 0, stream>>>(score, xb, pb);
    fc1_kernel<<<dim3(12, 6), 256, 0, stream>>>(pb, wtfc1, uu);
    head2_kernel<<<BBg, 256, 0, stream>>>(uu, fc1_b, fc2_w, fc2_b, outp);
}